// Round 1
// baseline (468.412 us; speedup 1.0000x reference)
//
#include <hip/hip_runtime.h>
#include <math.h>

#define BB 2
#define CC 128
#define LL 13824        // 24*24*24
#define DI 256          // d_inner
#define NST 16          // d_state
#define NCH 128         // scan chunks
#define TCH 108         // LL / NCH

__device__ __forceinline__ float silu_f(float x) { return x / (1.f + __expf(-x)); }

// ---------------- K1: LayerNorm + GEMM1 (xn @ W_in^T) -> xi, z ----------------
// 32 rows/block. LDS row stride 132 (16B aligned, de-conflicted).
__global__ __launch_bounds__(256) void k_ln_gemm(
    const float* __restrict__ x, const float* __restrict__ ln_w, const float* __restrict__ ln_b,
    const float* __restrict__ W_in, float* __restrict__ xi, float* __restrict__ z)
{
    __shared__ float xl[32 * 132];
    const int tid = threadIdx.x;
    const int bb = blockIdx.x / 432;
    const int l0 = (blockIdx.x % 432) * 32;
    const float* xb = x + (size_t)bb * CC * LL;

    // load (coalesced on l), store transposed per-row
    for (int i = tid; i < 32 * 128; i += 256) {
        int c = i >> 5, li = i & 31;
        xl[li * 132 + c] = xb[(size_t)c * LL + l0 + li];
    }
    __syncthreads();
    // layernorm: 8 threads per row
    {
        int row = tid >> 3, g = tid & 7;
        float s = 0.f, sq = 0.f;
        for (int k = g; k < 128; k += 8) { float v = xl[row * 132 + k]; s += v; sq += v * v; }
        s += __shfl_xor(s, 1); sq += __shfl_xor(sq, 1);
        s += __shfl_xor(s, 2); sq += __shfl_xor(sq, 2);
        s += __shfl_xor(s, 4); sq += __shfl_xor(sq, 4);
        float mu = s * (1.f / 128.f);
        float var = sq * (1.f / 128.f) - mu * mu;
        float rs = rsqrtf(var + 1e-5f);
        for (int k = g; k < 128; k += 8) {
            float v = xl[row * 132 + k];
            xl[row * 132 + k] = (v - mu) * rs * ln_w[k] + ln_b[k];
        }
    }
    __syncthreads();
    // GEMM: 128 col-threads x 4 cols, 2 row-halves x 16 rows
    const int ct = tid & 127, half = tid >> 7;
    const int n0 = ct * 4;
    const int r0 = half * 16;
    float acc[16][4];
    #pragma unroll
    for (int r = 0; r < 16; r++) { acc[r][0] = 0.f; acc[r][1] = 0.f; acc[r][2] = 0.f; acc[r][3] = 0.f; }
    for (int k = 0; k < 128; k += 4) {
        float4 w0 = *(const float4*)&W_in[(n0 + 0) * 128 + k];
        float4 w1 = *(const float4*)&W_in[(n0 + 1) * 128 + k];
        float4 w2 = *(const float4*)&W_in[(n0 + 2) * 128 + k];
        float4 w3 = *(const float4*)&W_in[(n0 + 3) * 128 + k];
        #pragma unroll
        for (int r = 0; r < 16; r++) {
            float4 a = *(const float4*)&xl[(r0 + r) * 132 + k];
            acc[r][0] += a.x * w0.x + a.y * w0.y + a.z * w0.z + a.w * w0.w;
            acc[r][1] += a.x * w1.x + a.y * w1.y + a.z * w1.z + a.w * w1.w;
            acc[r][2] += a.x * w2.x + a.y * w2.y + a.z * w2.z + a.w * w2.w;
            acc[r][3] += a.x * w3.x + a.y * w3.y + a.z * w3.z + a.w * w3.w;
        }
    }
    size_t rowbase = (size_t)bb * LL + l0 + r0;
    float* dst = (n0 < 256) ? xi : z;
    int nn = (n0 < 256) ? n0 : n0 - 256;
    #pragma unroll
    for (int r = 0; r < 16; r++) {
        float4 v = make_float4(acc[r][0], acc[r][1], acc[r][2], acc[r][3]);
        *(float4*)&dst[(rowbase + r) * 256 + nn] = v;
    }
}

// ---------------- K2: causal depthwise conv(4) + bias + SiLU -> u ----------------
__global__ __launch_bounds__(256) void k_conv(
    const float* __restrict__ xi, const float* __restrict__ conv_w, const float* __restrict__ conv_b,
    float* __restrict__ u)
{
    int idx = blockIdx.x * 256 + threadIdx.x; // (row, d)
    int d = idx & 255;
    int row = idx >> 8;       // b*LL + t
    int t = row % LL;
    float acc = conv_b[d];
    #pragma unroll
    for (int k = 0; k < 4; k++) {
        int tt = t - 3 + k;
        if (tt >= 0) acc += xi[(size_t)(row - 3 + k) * 256 + d] * conv_w[d * 4 + k];
    }
    u[idx] = silu_f(acc);
}

// ---------------- K3: x_dbl = u @ W_x^T ; Bs, Cs out; delta = softplus(dt_r@W_dt^T+b_dt) ----
__global__ __launch_bounds__(256) void k_xdbl(
    const float* __restrict__ u, const float* __restrict__ W_x, const float* __restrict__ W_dt,
    const float* __restrict__ b_dt, float* __restrict__ Bs, float* __restrict__ Cs,
    float* __restrict__ delta)
{
    __shared__ float u_l[16 * 260];
    __shared__ float wx[40 * 260];
    __shared__ float xdbl[16 * 40];
    __shared__ float wdt[256 * 9];
    __shared__ float bdt[256];
    const int tid = threadIdx.x;
    const int row0 = blockIdx.x * 16;

    for (int i = tid; i < 16 * 256; i += 256) {
        int r = i >> 8, k = i & 255;
        u_l[r * 260 + k] = u[((size_t)row0 + r) * 256 + k];
    }
    for (int i = tid; i < 40 * 256; i += 256) {
        int j = i >> 8, k = i & 255;
        wx[j * 260 + k] = W_x[i];
    }
    for (int i = tid; i < 256 * 8; i += 256) {
        int dd = i >> 3, jj = i & 7;
        wdt[dd * 9 + jj] = W_dt[i];
    }
    bdt[tid] = b_dt[tid];
    __syncthreads();

    // phase 2: 160 threads compute 2x2 tiles of the 16x40 x_dbl block
    if (tid < 160) {
        int rj = tid / 20, jt = tid % 20;
        int r0 = rj * 2, j0 = jt * 2;
        float a00 = 0.f, a01 = 0.f, a10 = 0.f, a11 = 0.f;
        for (int k = 0; k < 256; k += 4) {
            float4 ua = *(const float4*)&u_l[(r0 + 0) * 260 + k];
            float4 ub = *(const float4*)&u_l[(r0 + 1) * 260 + k];
            float4 w0 = *(const float4*)&wx[(j0 + 0) * 260 + k];
            float4 w1 = *(const float4*)&wx[(j0 + 1) * 260 + k];
            a00 += ua.x * w0.x + ua.y * w0.y + ua.z * w0.z + ua.w * w0.w;
            a01 += ua.x * w1.x + ua.y * w1.y + ua.z * w1.z + ua.w * w1.w;
            a10 += ub.x * w0.x + ub.y * w0.y + ub.z * w0.z + ub.w * w0.w;
            a11 += ub.x * w1.x + ub.y * w1.y + ub.z * w1.z + ub.w * w1.w;
        }
        #pragma unroll
        for (int rr = 0; rr < 2; rr++) {
            #pragma unroll
            for (int jj = 0; jj < 2; jj++) {
                float v = (rr == 0) ? ((jj == 0) ? a00 : a01) : ((jj == 0) ? a10 : a11);
                int r = r0 + rr, j = j0 + jj;
                xdbl[r * 40 + j] = v;
                int grow = row0 + r;
                if (j >= 8 && j < 24) Bs[(size_t)grow * 16 + (j - 8)] = v;
                else if (j >= 24)     Cs[(size_t)grow * 16 + (j - 24)] = v;
            }
        }
    }
    __syncthreads();

    // phase 3: delta
    for (int i = tid; i < 16 * 256; i += 256) {
        int r = i >> 8, dd = i & 255;
        float v = bdt[dd];
        #pragma unroll
        for (int jj = 0; jj < 8; jj++) v += xdbl[r * 40 + jj] * wdt[dd * 9 + jj];
        float sp = (v > 20.f) ? v : log1pf(expf(v));
        delta[((size_t)row0 + r) * 256 + dd] = sp;
    }
}

// ---------------- K4a: per-chunk scan summaries (prodA, accB) ----------------
// gid bits: s[0:4) d[4:12) b[12] c[13:20)
__global__ __launch_bounds__(256) void k_scanA(
    const float* __restrict__ delta, const float* __restrict__ u, const float* __restrict__ Bs,
    const float* __restrict__ A_log, float* __restrict__ prodA, float* __restrict__ accB)
{
    int gid = blockIdx.x * 256 + threadIdx.x;
    int s = gid & 15, dd = (gid >> 4) & 255, bb = (gid >> 12) & 1, c = gid >> 13;
    float Ac = -expf(A_log[dd * 16 + s]);
    float prod = 1.f, acc = 0.f;
    size_t rbase = (size_t)bb * LL + c * TCH;
    for (int tt = 0; tt < TCH; tt++) {
        size_t ro = rbase + tt;
        float dt = delta[ro * 256 + dd];
        float uu = u[ro * 256 + dd];
        float bs = Bs[ro * 16 + s];
        float a = __expf(dt * Ac);
        acc = a * acc + dt * uu * bs;
        prod *= a;
    }
    prodA[gid] = prod;
    accB[gid] = acc;
}

// ---------------- K4b: sequential chunk-prefix -> hstart ----------------
__global__ __launch_bounds__(256) void k_scanB(
    const float* __restrict__ prodA, const float* __restrict__ accB, float* __restrict__ hstart)
{
    int g = blockIdx.x * 256 + threadIdx.x; // 8192 = (b,d,s)
    float h = 0.f;
    for (int c = 0; c < NCH; c++) {
        hstart[c * 8192 + g] = h;
        h = prodA[c * 8192 + g] * h + accB[c * 8192 + g];
    }
}

// ---------------- K4c: recompute scan with correct h0, fuse y=(Σh·C + u·D)·silu(z) ----------
__global__ __launch_bounds__(256) void k_scanC(
    const float* __restrict__ delta, const float* __restrict__ u, const float* __restrict__ Bs,
    const float* __restrict__ Cs, const float* __restrict__ z, const float* __restrict__ A_log,
    const float* __restrict__ D_param, const float* __restrict__ hstart, float* __restrict__ y)
{
    int gid = blockIdx.x * 256 + threadIdx.x;
    int s = gid & 15, dd = (gid >> 4) & 255, bb = (gid >> 12) & 1, c = gid >> 13;
    float Ac = -expf(A_log[dd * 16 + s]);
    float Dp = D_param[dd];
    float h = hstart[gid];
    size_t rbase = (size_t)bb * LL + c * TCH;
    for (int tt = 0; tt < TCH; tt++) {
        size_t ro = rbase + tt;
        float dt = delta[ro * 256 + dd];
        float uu = u[ro * 256 + dd];
        float bs = Bs[ro * 16 + s];
        float cs = Cs[ro * 16 + s];
        float a = __expf(dt * Ac);
        h = a * h + dt * uu * bs;
        float p = h * cs;
        p += __shfl_xor(p, 1);
        p += __shfl_xor(p, 2);
        p += __shfl_xor(p, 4);
        p += __shfl_xor(p, 8);
        if (s == 0) {
            float zv = z[ro * 256 + dd];
            y[ro * 256 + dd] = (p + uu * Dp) * silu_f(zv);
        }
    }
}

// ---------------- K5: out = y @ W_out^T, transposed store to (B,C,L) ----------------
__global__ __launch_bounds__(256) void k_out(
    const float* __restrict__ y, const float* __restrict__ W_out, float* __restrict__ out)
{
    __shared__ float sm[64 * 260];
    const int tid = threadIdx.x;
    const int bb = blockIdx.x / 216;
    const int l0 = (blockIdx.x % 216) * 64;
    size_t row0 = (size_t)bb * LL + l0;
    for (int i = tid; i < 64 * 256; i += 256) {
        int r = i >> 8, k = i & 255;
        sm[r * 260 + k] = y[(row0 + r) * 256 + k];
    }
    __syncthreads();
    const int ct = tid & 63, rq = tid >> 6;
    const int c0 = ct * 2, r0 = rq * 16;
    float acc[16][2];
    #pragma unroll
    for (int r = 0; r < 16; r++) { acc[r][0] = 0.f; acc[r][1] = 0.f; }
    for (int k = 0; k < 256; k += 4) {
        float4 w0 = *(const float4*)&W_out[(c0 + 0) * 256 + k];
        float4 w1 = *(const float4*)&W_out[(c0 + 1) * 256 + k];
        #pragma unroll
        for (int r = 0; r < 16; r++) {
            float4 a = *(const float4*)&sm[(r0 + r) * 260 + k];
            acc[r][0] += a.x * w0.x + a.y * w0.y + a.z * w0.z + a.w * w0.w;
            acc[r][1] += a.x * w1.x + a.y * w1.y + a.z * w1.z + a.w * w1.w;
        }
    }
    __syncthreads();
    #pragma unroll
    for (int r = 0; r < 16; r++) {
        sm[(c0 + 0) * 66 + r0 + r] = acc[r][0];
        sm[(c0 + 1) * 66 + r0 + r] = acc[r][1];
    }
    __syncthreads();
    float* outb = out + (size_t)bb * CC * LL;
    for (int i = tid; i < 128 * 64; i += 256) {
        int cc2 = i >> 6, li = i & 63;
        outb[(size_t)cc2 * LL + l0 + li] = sm[cc2 * 66 + li];
    }
}

extern "C" void kernel_launch(void* const* d_in, const int* in_sizes, int n_in,
                              void* d_out, int out_size, void* d_ws, size_t ws_size,
                              hipStream_t stream)
{
    const float* x      = (const float*)d_in[0];
    const float* ln_w   = (const float*)d_in[1];
    const float* ln_b   = (const float*)d_in[2];
    const float* W_in   = (const float*)d_in[3];
    const float* conv_w = (const float*)d_in[4];
    const float* conv_b = (const float*)d_in[5];
    const float* W_x    = (const float*)d_in[6];
    const float* W_dt   = (const float*)d_in[7];
    const float* b_dt   = (const float*)d_in[8];
    const float* A_log  = (const float*)d_in[9];
    const float* D_par  = (const float*)d_in[10];
    const float* W_out  = (const float*)d_in[11];
    float* out = (float*)d_out;
    float* ws  = (float*)d_ws;

    const size_t NRD = (size_t)BB * LL * 256;   // 7,077,888
    float* xi    = ws;
    float* z     = ws + NRD;
    float* u     = ws + 2 * NRD;
    float* delta = ws + 3 * NRD;
    float* Bsb   = ws + 4 * NRD;
    float* Csb   = Bsb + (size_t)BB * LL * 16;
    float* prodA = Csb + (size_t)BB * LL * 16;
    float* accB  = prodA + (size_t)NCH * 8192;
    float* hst   = accB + (size_t)NCH * 8192;
    float* y     = xi;  // xi dead after conv

    k_ln_gemm<<<864, 256, 0, stream>>>(x, ln_w, ln_b, W_in, xi, z);
    k_conv<<<27648, 256, 0, stream>>>(xi, conv_w, conv_b, u);
    k_xdbl<<<1728, 256, 0, stream>>>(u, W_x, W_dt, b_dt, Bsb, Csb, delta);
    k_scanA<<<4096, 256, 0, stream>>>(delta, u, Bsb, A_log, prodA, accB);
    k_scanB<<<32, 256, 0, stream>>>(prodA, accB, hst);
    k_scanC<<<4096, 256, 0, stream>>>(delta, u, Bsb, Csb, z, A_log, D_par, hst, y);
    k_out<<<432, 256, 0, stream>>>(y, W_out, out);
}

// Round 2
// 444.936 us; speedup vs baseline: 1.0528x; 1.0528x over previous
//
#include <hip/hip_runtime.h>
#include <math.h>

#define BB 2
#define CC 128
#define LL 13824        // 24*24*24
#define DI 256          // d_inner
#define NST 16          // d_state
#define TCHMAX 108      // LL / 128 (max chunk length we ever use)

__device__ __forceinline__ float silu_f(float x) { return x / (1.f + __expf(-x)); }

// ---------------- K1: LayerNorm + GEMM1 (xn @ W_in^T) -> xi, z ----------------
__global__ __launch_bounds__(256) void k_ln_gemm(
    const float* __restrict__ x, const float* __restrict__ ln_w, const float* __restrict__ ln_b,
    const float* __restrict__ W_in, float* __restrict__ xi, float* __restrict__ z)
{
    __shared__ float xl[32 * 132];
    const int tid = threadIdx.x;
    const int bb = blockIdx.x / 432;
    const int l0 = (blockIdx.x % 432) * 32;
    const float* xb = x + (size_t)bb * CC * LL;

    for (int i = tid; i < 32 * 128; i += 256) {
        int c = i >> 5, li = i & 31;
        xl[li * 132 + c] = xb[(size_t)c * LL + l0 + li];
    }
    __syncthreads();
    {
        int row = tid >> 3, g = tid & 7;
        float s = 0.f, sq = 0.f;
        for (int k = g; k < 128; k += 8) { float v = xl[row * 132 + k]; s += v; sq += v * v; }
        s += __shfl_xor(s, 1); sq += __shfl_xor(sq, 1);
        s += __shfl_xor(s, 2); sq += __shfl_xor(sq, 2);
        s += __shfl_xor(s, 4); sq += __shfl_xor(sq, 4);
        float mu = s * (1.f / 128.f);
        float var = sq * (1.f / 128.f) - mu * mu;
        float rs = rsqrtf(var + 1e-5f);
        for (int k = g; k < 128; k += 8) {
            float v = xl[row * 132 + k];
            xl[row * 132 + k] = (v - mu) * rs * ln_w[k] + ln_b[k];
        }
    }
    __syncthreads();
    const int ct = tid & 127, half = tid >> 7;
    const int n0 = ct * 4;
    const int r0 = half * 16;
    float acc[16][4];
    #pragma unroll
    for (int r = 0; r < 16; r++) { acc[r][0] = 0.f; acc[r][1] = 0.f; acc[r][2] = 0.f; acc[r][3] = 0.f; }
    for (int k = 0; k < 128; k += 4) {
        float4 w0 = *(const float4*)&W_in[(n0 + 0) * 128 + k];
        float4 w1 = *(const float4*)&W_in[(n0 + 1) * 128 + k];
        float4 w2 = *(const float4*)&W_in[(n0 + 2) * 128 + k];
        float4 w3 = *(const float4*)&W_in[(n0 + 3) * 128 + k];
        #pragma unroll
        for (int r = 0; r < 16; r++) {
            float4 a = *(const float4*)&xl[(r0 + r) * 132 + k];
            acc[r][0] += a.x * w0.x + a.y * w0.y + a.z * w0.z + a.w * w0.w;
            acc[r][1] += a.x * w1.x + a.y * w1.y + a.z * w1.z + a.w * w1.w;
            acc[r][2] += a.x * w2.x + a.y * w2.y + a.z * w2.z + a.w * w2.w;
            acc[r][3] += a.x * w3.x + a.y * w3.y + a.z * w3.z + a.w * w3.w;
        }
    }
    size_t rowbase = (size_t)bb * LL + l0 + r0;
    float* dst = (n0 < 256) ? xi : z;
    int nn = (n0 < 256) ? n0 : n0 - 256;
    #pragma unroll
    for (int r = 0; r < 16; r++) {
        float4 v = make_float4(acc[r][0], acc[r][1], acc[r][2], acc[r][3]);
        *(float4*)&dst[(rowbase + r) * 256 + nn] = v;
    }
}

// ---------------- K2: causal depthwise conv(4) + bias + SiLU -> u ----------------
__global__ __launch_bounds__(256) void k_conv(
    const float* __restrict__ xi, const float* __restrict__ conv_w, const float* __restrict__ conv_b,
    float* __restrict__ u)
{
    int idx = blockIdx.x * 256 + threadIdx.x;
    int d = idx & 255;
    int row = idx >> 8;
    int t = row % LL;
    float acc = conv_b[d];
    #pragma unroll
    for (int k = 0; k < 4; k++) {
        int tt = t - 3 + k;
        if (tt >= 0) acc += xi[(size_t)(row - 3 + k) * 256 + d] * conv_w[d * 4 + k];
    }
    u[idx] = silu_f(acc);
}

// ---------------- K3: x_dbl = u @ W_x^T ; Bs, Cs; delta = softplus(dt_r@W_dt^T+b_dt) ----
__global__ __launch_bounds__(256) void k_xdbl(
    const float* __restrict__ u, const float* __restrict__ W_x, const float* __restrict__ W_dt,
    const float* __restrict__ b_dt, float* __restrict__ Bs, float* __restrict__ Cs,
    float* __restrict__ delta)
{
    __shared__ float u_l[16 * 260];
    __shared__ float wx[40 * 260];
    __shared__ float xdbl[16 * 40];
    __shared__ float wdt[256 * 9];
    __shared__ float bdt[256];
    const int tid = threadIdx.x;
    const int row0 = blockIdx.x * 16;

    for (int i = tid; i < 16 * 256; i += 256) {
        int r = i >> 8, k = i & 255;
        u_l[r * 260 + k] = u[((size_t)row0 + r) * 256 + k];
    }
    for (int i = tid; i < 40 * 256; i += 256) {
        int j = i >> 8, k = i & 255;
        wx[j * 260 + k] = W_x[i];
    }
    for (int i = tid; i < 256 * 8; i += 256) {
        int dd = i >> 3, jj = i & 7;
        wdt[dd * 9 + jj] = W_dt[i];
    }
    bdt[tid] = b_dt[tid];
    __syncthreads();

    if (tid < 160) {
        int rj = tid / 20, jt = tid % 20;
        int r0 = rj * 2, j0 = jt * 2;
        float a00 = 0.f, a01 = 0.f, a10 = 0.f, a11 = 0.f;
        for (int k = 0; k < 256; k += 4) {
            float4 ua = *(const float4*)&u_l[(r0 + 0) * 260 + k];
            float4 ub = *(const float4*)&u_l[(r0 + 1) * 260 + k];
            float4 w0 = *(const float4*)&wx[(j0 + 0) * 260 + k];
            float4 w1 = *(const float4*)&wx[(j0 + 1) * 260 + k];
            a00 += ua.x * w0.x + ua.y * w0.y + ua.z * w0.z + ua.w * w0.w;
            a01 += ua.x * w1.x + ua.y * w1.y + ua.z * w1.z + ua.w * w1.w;
            a10 += ub.x * w0.x + ub.y * w0.y + ub.z * w0.z + ub.w * w0.w;
            a11 += ub.x * w1.x + ub.y * w1.y + ub.z * w1.z + ub.w * w1.w;
        }
        #pragma unroll
        for (int rr = 0; rr < 2; rr++) {
            #pragma unroll
            for (int jj = 0; jj < 2; jj++) {
                float v = (rr == 0) ? ((jj == 0) ? a00 : a01) : ((jj == 0) ? a10 : a11);
                int r = r0 + rr, j = j0 + jj;
                xdbl[r * 40 + j] = v;
                int grow = row0 + r;
                if (j >= 8 && j < 24) Bs[(size_t)grow * 16 + (j - 8)] = v;
                else if (j >= 24)     Cs[(size_t)grow * 16 + (j - 24)] = v;
            }
        }
    }
    __syncthreads();

    for (int i = tid; i < 16 * 256; i += 256) {
        int r = i >> 8, dd = i & 255;
        float v = bdt[dd];
        #pragma unroll
        for (int jj = 0; jj < 8; jj++) v += xdbl[r * 40 + jj] * wdt[dd * 9 + jj];
        float sp = (v > 20.f) ? v : log1pf(expf(v));
        delta[((size_t)row0 + r) * 256 + dd] = sp;
    }
}

// ---------------- K4a: per-chunk scan summaries; thread=(b,chunk,d), 16 states in regs ----
__global__ __launch_bounds__(256) void k_scanA(
    const float* __restrict__ delta, const float* __restrict__ u, const float* __restrict__ Bs,
    const float* __restrict__ A_log, float* __restrict__ prodA, float* __restrict__ accB,
    int tch)
{
    __shared__ float bs_l[TCHMAX * 16];
    const int bb = blockIdx.x & 1;
    const int c  = blockIdx.x >> 1;
    const int dd = threadIdx.x;
    const size_t rbase = (size_t)bb * LL + (size_t)c * tch;

    {
        const float4* src = (const float4*)(Bs + rbase * 16);
        float4* dst = (float4*)bs_l;
        for (int i = threadIdx.x; i < tch * 4; i += 256) dst[i] = src[i];
    }
    __syncthreads();

    float Ac[16], h[16], pr[16];
    #pragma unroll
    for (int s = 0; s < 16; s++) {
        Ac[s] = -expf(A_log[dd * 16 + s]);
        h[s] = 0.f; pr[s] = 1.f;
    }
    for (int tt = 0; tt < tch; tt++) {
        size_t ro = rbase + tt;
        float dt = delta[ro * 256 + dd];
        float uu = u[ro * 256 + dd];
        float du = dt * uu;
        const float4* bv = (const float4*)&bs_l[tt * 16];
        float4 b0 = bv[0], b1 = bv[1], b2 = bv[2], b3 = bv[3];
        float bsv[16] = {b0.x,b0.y,b0.z,b0.w, b1.x,b1.y,b1.z,b1.w,
                         b2.x,b2.y,b2.z,b2.w, b3.x,b3.y,b3.z,b3.w};
        #pragma unroll
        for (int s = 0; s < 16; s++) {
            float a = __expf(dt * Ac[s]);
            h[s] = a * h[s] + du * bsv[s];
            pr[s] *= a;
        }
    }
    size_t base = (size_t)c * 8192 + bb * 4096 + dd * 16;
    #pragma unroll
    for (int q = 0; q < 4; q++) {
        *(float4*)&prodA[base + q * 4] = make_float4(pr[q*4+0], pr[q*4+1], pr[q*4+2], pr[q*4+3]);
        *(float4*)&accB [base + q * 4] = make_float4(h [q*4+0], h [q*4+1], h [q*4+2], h [q*4+3]);
    }
}

// ---------------- K4b: sequential chunk-prefix; accB overwritten in-place with hstart ----
__global__ __launch_bounds__(256) void k_scanB(
    const float* __restrict__ prodA, float* __restrict__ accB, int nch)
{
    int g = blockIdx.x * 256 + threadIdx.x;   // 8192 = (b,d,s)
    float h = 0.f;
    for (int c = 0; c < nch; c++) {
        float a = prodA[(size_t)c * 8192 + g];
        float bv = accB[(size_t)c * 8192 + g];
        accB[(size_t)c * 8192 + g] = h;       // h at start of chunk c
        h = a * h + bv;
    }
}

// ---------------- K4c: final scan with correct h0; fuse y=(Σh·C + u·D)·silu(z) ----------
__global__ __launch_bounds__(256) void k_scanC(
    const float* __restrict__ delta, const float* __restrict__ u, const float* __restrict__ Bs,
    const float* __restrict__ Cs, const float* __restrict__ z, const float* __restrict__ A_log,
    const float* __restrict__ D_param, const float* __restrict__ hstart, float* __restrict__ y,
    int tch)
{
    __shared__ float bs_l[TCHMAX * 16];
    __shared__ float cs_l[TCHMAX * 16];
    const int bb = blockIdx.x & 1;
    const int c  = blockIdx.x >> 1;
    const int dd = threadIdx.x;
    const size_t rbase = (size_t)bb * LL + (size_t)c * tch;

    {
        const float4* srcB = (const float4*)(Bs + rbase * 16);
        const float4* srcC = (const float4*)(Cs + rbase * 16);
        float4* dstB = (float4*)bs_l;
        float4* dstC = (float4*)cs_l;
        for (int i = threadIdx.x; i < tch * 4; i += 256) { dstB[i] = srcB[i]; dstC[i] = srcC[i]; }
    }
    __syncthreads();

    float Ac[16], h[16];
    #pragma unroll
    for (int s = 0; s < 16; s++) Ac[s] = -expf(A_log[dd * 16 + s]);
    size_t hbase = (size_t)c * 8192 + bb * 4096 + dd * 16;
    #pragma unroll
    for (int q = 0; q < 4; q++) {
        float4 hv = *(const float4*)&hstart[hbase + q * 4];
        h[q*4+0] = hv.x; h[q*4+1] = hv.y; h[q*4+2] = hv.z; h[q*4+3] = hv.w;
    }
    const float Dp = D_param[dd];

    for (int tt = 0; tt < tch; tt++) {
        size_t ro = rbase + tt;
        float dt = delta[ro * 256 + dd];
        float uu = u[ro * 256 + dd];
        float du = dt * uu;
        const float4* bv = (const float4*)&bs_l[tt * 16];
        const float4* cv = (const float4*)&cs_l[tt * 16];
        float4 b0 = bv[0], b1 = bv[1], b2 = bv[2], b3 = bv[3];
        float4 c0 = cv[0], c1 = cv[1], c2 = cv[2], c3 = cv[3];
        float bsv[16] = {b0.x,b0.y,b0.z,b0.w, b1.x,b1.y,b1.z,b1.w,
                         b2.x,b2.y,b2.z,b2.w, b3.x,b3.y,b3.z,b3.w};
        float csv[16] = {c0.x,c0.y,c0.z,c0.w, c1.x,c1.y,c1.z,c1.w,
                         c2.x,c2.y,c2.z,c2.w, c3.x,c3.y,c3.z,c3.w};
        float p0 = 0.f, p1 = 0.f, p2 = 0.f, p3 = 0.f;
        #pragma unroll
        for (int q = 0; q < 4; q++) {
            float a0 = __expf(dt * Ac[q*4+0]);
            float a1 = __expf(dt * Ac[q*4+1]);
            float a2 = __expf(dt * Ac[q*4+2]);
            float a3 = __expf(dt * Ac[q*4+3]);
            h[q*4+0] = a0 * h[q*4+0] + du * bsv[q*4+0];
            h[q*4+1] = a1 * h[q*4+1] + du * bsv[q*4+1];
            h[q*4+2] = a2 * h[q*4+2] + du * bsv[q*4+2];
            h[q*4+3] = a3 * h[q*4+3] + du * bsv[q*4+3];
            p0 += h[q*4+0] * csv[q*4+0];
            p1 += h[q*4+1] * csv[q*4+1];
            p2 += h[q*4+2] * csv[q*4+2];
            p3 += h[q*4+3] * csv[q*4+3];
        }
        float p = (p0 + p1) + (p2 + p3);
        float zv = z[ro * 256 + dd];
        y[ro * 256 + dd] = (p + uu * Dp) * silu_f(zv);
    }
}

// ---------------- K5: out = y @ W_out^T, transposed store to (B,C,L) ----------------
__global__ __launch_bounds__(256) void k_out(
    const float* __restrict__ y, const float* __restrict__ W_out, float* __restrict__ out)
{
    __shared__ float sm[64 * 260];
    const int tid = threadIdx.x;
    const int bb = blockIdx.x / 216;
    const int l0 = (blockIdx.x % 216) * 64;
    size_t row0 = (size_t)bb * LL + l0;
    for (int i = tid; i < 64 * 256; i += 256) {
        int r = i >> 8, k = i & 255;
        sm[r * 260 + k] = y[(row0 + r) * 256 + k];
    }
    __syncthreads();
    const int ct = tid & 63, rq = tid >> 6;
    const int c0 = ct * 2, r0 = rq * 16;
    float acc[16][2];
    #pragma unroll
    for (int r = 0; r < 16; r++) { acc[r][0] = 0.f; acc[r][1] = 0.f; }
    for (int k = 0; k < 256; k += 4) {
        float4 w0 = *(const float4*)&W_out[(c0 + 0) * 256 + k];
        float4 w1 = *(const float4*)&W_out[(c0 + 1) * 256 + k];
        #pragma unroll
        for (int r = 0; r < 16; r++) {
            float4 a = *(const float4*)&sm[(r0 + r) * 260 + k];
            acc[r][0] += a.x * w0.x + a.y * w0.y + a.z * w0.z + a.w * w0.w;
            acc[r][1] += a.x * w1.x + a.y * w1.y + a.z * w1.z + a.w * w1.w;
        }
    }
    __syncthreads();
    #pragma unroll
    for (int r = 0; r < 16; r++) {
        sm[(c0 + 0) * 66 + r0 + r] = acc[r][0];
        sm[(c0 + 1) * 66 + r0 + r] = acc[r][1];
    }
    __syncthreads();
    float* outb = out + (size_t)bb * CC * LL;
    for (int i = tid; i < 128 * 64; i += 256) {
        int cc2 = i >> 6, li = i & 63;
        outb[(size_t)cc2 * LL + l0 + li] = sm[cc2 * 66 + li];
    }
}

extern "C" void kernel_launch(void* const* d_in, const int* in_sizes, int n_in,
                              void* d_out, int out_size, void* d_ws, size_t ws_size,
                              hipStream_t stream)
{
    const float* x      = (const float*)d_in[0];
    const float* ln_w   = (const float*)d_in[1];
    const float* ln_b   = (const float*)d_in[2];
    const float* W_in   = (const float*)d_in[3];
    const float* conv_w = (const float*)d_in[4];
    const float* conv_b = (const float*)d_in[5];
    const float* W_x    = (const float*)d_in[6];
    const float* W_dt   = (const float*)d_in[7];
    const float* b_dt   = (const float*)d_in[8];
    const float* A_log  = (const float*)d_in[9];
    const float* D_par  = (const float*)d_in[10];
    const float* W_out  = (const float*)d_in[11];
    float* out = (float*)d_out;
    float* ws  = (float*)d_ws;

    const size_t NRD = (size_t)BB * LL * 256;     // 7,077,888 floats
    const size_t NBC = (size_t)BB * LL * 16;      //   442,368 floats
    float* xi    = ws;
    float* z     = ws + NRD;
    float* u     = ws + 2 * NRD;
    float* delta = ws + 3 * NRD;
    float* Bsb   = ws + 4 * NRD;
    float* Csb   = Bsb + NBC;
    float* prodA = Csb + NBC;
    float* y     = xi;  // xi dead after conv

    // pick chunk count by available workspace (prodA + accB = 2 * nch * 8192 floats)
    size_t avail_f = ws_size / 4;
    size_t fixed_f = 4 * NRD + 2 * NBC;
    int nch = 512;
    while (nch > 128 && fixed_f + 2 * (size_t)nch * 8192 > avail_f) nch >>= 1;
    int tch = LL / nch;
    float* accB = prodA + (size_t)nch * 8192;   // also becomes hstart after k_scanB

    k_ln_gemm<<<864, 256, 0, stream>>>(x, ln_w, ln_b, W_in, xi, z);
    k_conv<<<27648, 256, 0, stream>>>(xi, conv_w, conv_b, u);
    k_xdbl<<<1728, 256, 0, stream>>>(u, W_x, W_dt, b_dt, Bsb, Csb, delta);
    k_scanA<<<2 * nch, 256, 0, stream>>>(delta, u, Bsb, A_log, prodA, accB, tch);
    k_scanB<<<32, 256, 0, stream>>>(prodA, accB, nch);
    k_scanC<<<2 * nch, 256, 0, stream>>>(delta, u, Bsb, Csb, z, A_log, D_par, accB, y, tch);
    k_out<<<432, 256, 0, stream>>>(y, W_out, out);
}

// Round 3
// 329.414 us; speedup vs baseline: 1.4220x; 1.3507x over previous
//
#include <hip/hip_runtime.h>
#include <math.h>

#define BB 2
#define CC 128
#define LL 13824        // 24*24*24
#define DI 256          // d_inner
#define NST 16          // d_state
#define NCH 512         // scan chunks
#define TCH 27          // LL / NCH

__device__ __forceinline__ float silu_f(float x) { return x / (1.f + __expf(-x)); }

// ---------------- K1: LayerNorm + GEMM1 (xn @ W_in^T) -> xi, z ----------------
__global__ __launch_bounds__(256) void k_ln_gemm(
    const float* __restrict__ x, const float* __restrict__ ln_w, const float* __restrict__ ln_b,
    const float* __restrict__ W_in, float* __restrict__ xi, float* __restrict__ z)
{
    __shared__ float xl[32 * 132];
    const int tid = threadIdx.x;
    const int bb = blockIdx.x / 432;
    const int l0 = (blockIdx.x % 432) * 32;
    const float* xb = x + (size_t)bb * CC * LL;

    for (int i = tid; i < 32 * 128; i += 256) {
        int c = i >> 5, li = i & 31;
        xl[li * 132 + c] = xb[(size_t)c * LL + l0 + li];
    }
    __syncthreads();
    {
        int row = tid >> 3, g = tid & 7;
        float s = 0.f, sq = 0.f;
        for (int k = g; k < 128; k += 8) { float v = xl[row * 132 + k]; s += v; sq += v * v; }
        s += __shfl_xor(s, 1); sq += __shfl_xor(sq, 1);
        s += __shfl_xor(s, 2); sq += __shfl_xor(sq, 2);
        s += __shfl_xor(s, 4); sq += __shfl_xor(sq, 4);
        float mu = s * (1.f / 128.f);
        float var = sq * (1.f / 128.f) - mu * mu;
        float rs = rsqrtf(var + 1e-5f);
        for (int k = g; k < 128; k += 8) {
            float v = xl[row * 132 + k];
            xl[row * 132 + k] = (v - mu) * rs * ln_w[k] + ln_b[k];
        }
    }
    __syncthreads();
    const int ct = tid & 127, half = tid >> 7;
    const int n0 = ct * 4;
    const int r0 = half * 16;
    float acc[16][4];
    #pragma unroll
    for (int r = 0; r < 16; r++) { acc[r][0] = 0.f; acc[r][1] = 0.f; acc[r][2] = 0.f; acc[r][3] = 0.f; }
    for (int k = 0; k < 128; k += 4) {
        float4 w0 = *(const float4*)&W_in[(n0 + 0) * 128 + k];
        float4 w1 = *(const float4*)&W_in[(n0 + 1) * 128 + k];
        float4 w2 = *(const float4*)&W_in[(n0 + 2) * 128 + k];
        float4 w3 = *(const float4*)&W_in[(n0 + 3) * 128 + k];
        #pragma unroll
        for (int r = 0; r < 16; r++) {
            float4 a = *(const float4*)&xl[(r0 + r) * 132 + k];
            acc[r][0] += a.x * w0.x + a.y * w0.y + a.z * w0.z + a.w * w0.w;
            acc[r][1] += a.x * w1.x + a.y * w1.y + a.z * w1.z + a.w * w1.w;
            acc[r][2] += a.x * w2.x + a.y * w2.y + a.z * w2.z + a.w * w2.w;
            acc[r][3] += a.x * w3.x + a.y * w3.y + a.z * w3.z + a.w * w3.w;
        }
    }
    size_t rowbase = (size_t)bb * LL + l0 + r0;
    float* dst = (n0 < 256) ? xi : z;
    int nn = (n0 < 256) ? n0 : n0 - 256;
    #pragma unroll
    for (int r = 0; r < 16; r++) {
        float4 v = make_float4(acc[r][0], acc[r][1], acc[r][2], acc[r][3]);
        *(float4*)&dst[(rowbase + r) * 256 + nn] = v;
    }
}

// ---------------- K2: causal depthwise conv(4) + bias + SiLU -> u (4 t per thread) -------
__global__ __launch_bounds__(256) void k_conv(
    const float* __restrict__ xi, const float* __restrict__ conv_w, const float* __restrict__ conv_b,
    float* __restrict__ u)
{
    int idx = blockIdx.x * 256 + threadIdx.x;
    int d = idx & 255;
    int q = idx >> 8;                  // b * (LL/4) + t4
    int b = q / (LL / 4);
    int t0 = (q % (LL / 4)) * 4;
    size_t base = ((size_t)b * LL + t0) * 256 + d;
    float w0 = conv_w[d * 4 + 0], w1 = conv_w[d * 4 + 1];
    float w2 = conv_w[d * 4 + 2], w3 = conv_w[d * 4 + 3];
    float cb = conv_b[d];
    float x0, x1, x2;
    if (t0 == 0) { x0 = 0.f; x1 = 0.f; x2 = 0.f; }
    else { x0 = xi[base - 3 * 256]; x1 = xi[base - 2 * 256]; x2 = xi[base - 256]; }
    float x3 = xi[base];
    float x4 = xi[base + 256];
    float x5 = xi[base + 2 * 256];
    float x6 = xi[base + 3 * 256];
    u[base]           = silu_f(cb + w0 * x0 + w1 * x1 + w2 * x2 + w3 * x3);
    u[base + 256]     = silu_f(cb + w0 * x1 + w1 * x2 + w2 * x3 + w3 * x4);
    u[base + 2 * 256] = silu_f(cb + w0 * x2 + w1 * x3 + w2 * x4 + w3 * x5);
    u[base + 3 * 256] = silu_f(cb + w0 * x3 + w1 * x4 + w2 * x5 + w3 * x6);
}

// ---------------- K3: x_dbl = u @ W_x^T ; Bs, Cs; delta = softplus(dt_r@W_dt^T+b_dt) ----
// 128 rows/block, 216 blocks. Thread = (rt 0..31) x (ct 0..7): 4 rows x 5 cols.
__global__ __launch_bounds__(256) void k_xdbl(
    const float* __restrict__ u, const float* __restrict__ W_x, const float* __restrict__ W_dt,
    const float* __restrict__ b_dt, float* __restrict__ Bs, float* __restrict__ Cs,
    float* __restrict__ delta)
{
    __shared__ float u_l[128 * 64];     // XOR-swizzled: float4 col kq stored at kq ^ ((r>>2)&7)
    __shared__ float wx[40 * 68];
    __shared__ float xdbl[128 * 41];
    __shared__ float wdt[256 * 9];
    const int tid = threadIdx.x;
    const size_t row0 = (size_t)blockIdx.x * 128;

    for (int i = tid; i < 2048; i += 256) wdt[(i >> 3) * 9 + (i & 7)] = W_dt[i];

    const int rt = tid >> 3;   // 0..31 -> rows rt*4 .. rt*4+3
    const int ct = tid & 7;    // 0..7  -> cols ct*5 .. ct*5+4
    float acc[4][5];
    #pragma unroll
    for (int r = 0; r < 4; r++)
        #pragma unroll
        for (int j = 0; j < 5; j++) acc[r][j] = 0.f;

    for (int kt = 0; kt < 4; kt++) {
        __syncthreads();
        for (int i = tid; i < 2048; i += 256) {      // u tile: 128 rows x 64 k
            int r = i >> 4, kq = i & 15;
            float4 v = *(const float4*)&u[(row0 + r) * 256 + kt * 64 + kq * 4];
            *(float4*)&u_l[r * 64 + ((kq ^ ((r >> 2) & 7)) << 2)] = v;
        }
        for (int i = tid; i < 640; i += 256) {       // wx tile: 40 x 64
            int j = i >> 4, kq = i & 15;
            *(float4*)&wx[j * 68 + kq * 4] = *(const float4*)&W_x[j * 256 + kt * 64 + kq * 4];
        }
        __syncthreads();
        #pragma unroll 4
        for (int kq = 0; kq < 16; kq++) {
            float4 a[4], w[5];
            #pragma unroll
            for (int rr = 0; rr < 4; rr++) {
                int r = rt * 4 + rr;
                a[rr] = *(const float4*)&u_l[r * 64 + ((kq ^ (rt & 7)) << 2)];
            }
            #pragma unroll
            for (int jj = 0; jj < 5; jj++)
                w[jj] = *(const float4*)&wx[(ct * 5 + jj) * 68 + kq * 4];
            #pragma unroll
            for (int rr = 0; rr < 4; rr++)
                #pragma unroll
                for (int jj = 0; jj < 5; jj++)
                    acc[rr][jj] += a[rr].x * w[jj].x + a[rr].y * w[jj].y
                                 + a[rr].z * w[jj].z + a[rr].w * w[jj].w;
        }
    }
    __syncthreads();
    #pragma unroll
    for (int rr = 0; rr < 4; rr++) {
        int r = rt * 4 + rr;
        size_t grow = row0 + r;
        #pragma unroll
        for (int jj = 0; jj < 5; jj++) {
            int j = ct * 5 + jj;
            float v = acc[rr][jj];
            xdbl[r * 41 + j] = v;
            if (j >= 8 && j < 24)      Bs[grow * 16 + (j - 8)]  = v;
            else if (j >= 24)          Cs[grow * 16 + (j - 24)] = v;
        }
    }
    __syncthreads();
    for (int i = tid; i < 128 * 256; i += 256) {
        int r = i >> 8, dd = i & 255;
        float v = b_dt[dd];
        #pragma unroll
        for (int jj = 0; jj < 8; jj++) v += xdbl[r * 41 + jj] * wdt[dd * 9 + jj];
        float sp = (v > 20.f) ? v : log1pf(expf(v));
        delta[(row0 + r) * 256 + dd] = sp;
    }
}

// ---------------- K4a: per-chunk scan summaries; thread=(b,chunk,d), 16 states in regs ----
__global__ __launch_bounds__(256) void k_scanA(
    const float* __restrict__ delta, const float* __restrict__ u, const float* __restrict__ Bs,
    const float* __restrict__ A_log, float* __restrict__ prodA, float* __restrict__ accB)
{
    __shared__ float bs_l[TCH * 16];
    const int bb = blockIdx.x & 1;
    const int c  = blockIdx.x >> 1;
    const int dd = threadIdx.x;
    const size_t rbase = (size_t)bb * LL + (size_t)c * TCH;

    {
        const float4* src = (const float4*)(Bs + rbase * 16);
        float4* dst = (float4*)bs_l;
        for (int i = threadIdx.x; i < TCH * 4; i += 256) dst[i] = src[i];
    }
    __syncthreads();

    float Ac[16], h[16], pr[16];
    #pragma unroll
    for (int s = 0; s < 16; s++) {
        Ac[s] = -expf(A_log[dd * 16 + s]);
        h[s] = 0.f; pr[s] = 1.f;
    }
    for (int tt = 0; tt < TCH; tt++) {
        size_t ro = rbase + tt;
        float dt = delta[ro * 256 + dd];
        float uu = u[ro * 256 + dd];
        float du = dt * uu;
        const float4* bv = (const float4*)&bs_l[tt * 16];
        float4 b0 = bv[0], b1 = bv[1], b2 = bv[2], b3 = bv[3];
        float bsv[16] = {b0.x,b0.y,b0.z,b0.w, b1.x,b1.y,b1.z,b1.w,
                         b2.x,b2.y,b2.z,b2.w, b3.x,b3.y,b3.z,b3.w};
        #pragma unroll
        for (int s = 0; s < 16; s++) {
            float a = __expf(dt * Ac[s]);
            h[s] = a * h[s] + du * bsv[s];
            pr[s] *= a;
        }
    }
    size_t base = (size_t)c * 8192 + bb * 4096 + dd * 16;
    #pragma unroll
    for (int q = 0; q < 4; q++) {
        *(float4*)&prodA[base + q * 4] = make_float4(pr[q*4+0], pr[q*4+1], pr[q*4+2], pr[q*4+3]);
        *(float4*)&accB [base + q * 4] = make_float4(h [q*4+0], h [q*4+1], h [q*4+2], h [q*4+3]);
    }
}

// ---------------- K4b: block-parallel chunk-prefix; accB overwritten with hstart ---------
// block = (b,d): 16 chains (s) x 512 chunks, scanned hierarchically in LDS.
__global__ __launch_bounds__(256) void k_scanB(
    const float* __restrict__ prodA, float* __restrict__ accB)
{
    __shared__ float sA[16 * 528];      // [s][c + c/32] padded
    __shared__ float sB[16 * 528];
    __shared__ float segA[16][17];
    __shared__ float segB[16][17];
    __shared__ float segH[16][17];
    const int bb = blockIdx.x >> 8;
    const int dd = blockIdx.x & 255;
    const int t = threadIdx.x;
    const size_t gbase = (size_t)bb * 4096 + dd * 16;

    for (int i = t; i < 2048; i += 256) {       // c = i>>2, sq = i&3 (4 states per float4)
        int c = i >> 2, sq = i & 3;
        size_t ga = (size_t)c * 8192 + gbase + sq * 4;
        float4 a = *(const float4*)&prodA[ga];
        float4 b = *(const float4*)&accB[ga];
        int cc = c + (c >> 5);
        sA[(4*sq+0) * 528 + cc] = a.x; sA[(4*sq+1) * 528 + cc] = a.y;
        sA[(4*sq+2) * 528 + cc] = a.z; sA[(4*sq+3) * 528 + cc] = a.w;
        sB[(4*sq+0) * 528 + cc] = b.x; sB[(4*sq+1) * 528 + cc] = b.y;
        sB[(4*sq+2) * 528 + cc] = b.z; sB[(4*sq+3) * 528 + cc] = b.w;
    }
    __syncthreads();

    const int s   = t >> 4;     // 0..15 chain
    const int seg = t & 15;     // 0..15 segment of 32 chunks
    const int base = s * 528;
    const int c0 = seg * 32;
    float A = 1.f, Bv = 0.f;
    for (int k = 0; k < 32; k++) {
        int cc = c0 + seg + k;              // c + (c>>5), c = c0+k
        float a = sA[base + cc];
        float b = sB[base + cc];
        A *= a;
        Bv = a * Bv + b;
    }
    segA[s][seg] = A; segB[s][seg] = Bv;
    __syncthreads();
    if (seg == 0) {
        float h = 0.f;
        #pragma unroll
        for (int g = 0; g < 16; g++) {
            segH[s][g] = h;
            h = segA[s][g] * h + segB[s][g];
        }
    }
    __syncthreads();
    float h = segH[s][seg];
    for (int k = 0; k < 32; k++) {
        int c = c0 + k;
        int cc = c + seg;
        float a = sA[base + cc];
        float b = sB[base + cc];
        accB[(size_t)c * 8192 + gbase + s] = h;
        h = a * h + b;
    }
}

// ---------------- K4c: final scan with correct h0; fuse y=(Σh·C + u·D)·silu(z) ----------
__global__ __launch_bounds__(256) void k_scanC(
    const float* __restrict__ delta, const float* __restrict__ u, const float* __restrict__ Bs,
    const float* __restrict__ Cs, const float* __restrict__ z, const float* __restrict__ A_log,
    const float* __restrict__ D_param, const float* __restrict__ hstart, float* __restrict__ y)
{
    __shared__ float bs_l[TCH * 16];
    __shared__ float cs_l[TCH * 16];
    const int bb = blockIdx.x & 1;
    const int c  = blockIdx.x >> 1;
    const int dd = threadIdx.x;
    const size_t rbase = (size_t)bb * LL + (size_t)c * TCH;

    {
        const float4* srcB = (const float4*)(Bs + rbase * 16);
        const float4* srcC = (const float4*)(Cs + rbase * 16);
        float4* dstB = (float4*)bs_l;
        float4* dstC = (float4*)cs_l;
        for (int i = threadIdx.x; i < TCH * 4; i += 256) { dstB[i] = srcB[i]; dstC[i] = srcC[i]; }
    }
    __syncthreads();

    float Ac[16], h[16];
    #pragma unroll
    for (int s = 0; s < 16; s++) Ac[s] = -expf(A_log[dd * 16 + s]);
    size_t hbase = (size_t)c * 8192 + bb * 4096 + dd * 16;
    #pragma unroll
    for (int q = 0; q < 4; q++) {
        float4 hv = *(const float4*)&hstart[hbase + q * 4];
        h[q*4+0] = hv.x; h[q*4+1] = hv.y; h[q*4+2] = hv.z; h[q*4+3] = hv.w;
    }
    const float Dp = D_param[dd];

    for (int tt = 0; tt < TCH; tt++) {
        size_t ro = rbase + tt;
        float dt = delta[ro * 256 + dd];
        float uu = u[ro * 256 + dd];
        float du = dt * uu;
        const float4* bv = (const float4*)&bs_l[tt * 16];
        const float4* cv = (const float4*)&cs_l[tt * 16];
        float4 b0 = bv[0], b1 = bv[1], b2 = bv[2], b3 = bv[3];
        float4 c0 = cv[0], c1 = cv[1], c2 = cv[2], c3 = cv[3];
        float bsv[16] = {b0.x,b0.y,b0.z,b0.w, b1.x,b1.y,b1.z,b1.w,
                         b2.x,b2.y,b2.z,b2.w, b3.x,b3.y,b3.z,b3.w};
        float csv[16] = {c0.x,c0.y,c0.z,c0.w, c1.x,c1.y,c1.z,c1.w,
                         c2.x,c2.y,c2.z,c2.w, c3.x,c3.y,c3.z,c3.w};
        float p0 = 0.f, p1 = 0.f, p2 = 0.f, p3 = 0.f;
        #pragma unroll
        for (int q = 0; q < 4; q++) {
            float a0 = __expf(dt * Ac[q*4+0]);
            float a1 = __expf(dt * Ac[q*4+1]);
            float a2 = __expf(dt * Ac[q*4+2]);
            float a3 = __expf(dt * Ac[q*4+3]);
            h[q*4+0] = a0 * h[q*4+0] + du * bsv[q*4+0];
            h[q*4+1] = a1 * h[q*4+1] + du * bsv[q*4+1];
            h[q*4+2] = a2 * h[q*4+2] + du * bsv[q*4+2];
            h[q*4+3] = a3 * h[q*4+3] + du * bsv[q*4+3];
            p0 += h[q*4+0] * csv[q*4+0];
            p1 += h[q*4+1] * csv[q*4+1];
            p2 += h[q*4+2] * csv[q*4+2];
            p3 += h[q*4+3] * csv[q*4+3];
        }
        float p = (p0 + p1) + (p2 + p3);
        float zv = z[ro * 256 + dd];
        y[ro * 256 + dd] = (p + uu * Dp) * silu_f(zv);
    }
}

// ---------------- K5: out = y @ W_out^T, transposed store to (B,C,L) ----------------
__global__ __launch_bounds__(256) void k_out(
    const float* __restrict__ y, const float* __restrict__ W_out, float* __restrict__ out)
{
    __shared__ float sm[64 * 260];
    const int tid = threadIdx.x;
    const int bb = blockIdx.x / 216;
    const int l0 = (blockIdx.x % 216) * 64;
    size_t row0 = (size_t)bb * LL + l0;
    for (int i = tid; i < 64 * 256; i += 256) {
        int r = i >> 8, k = i & 255;
        sm[r * 260 + k] = y[(row0 + r) * 256 + k];
    }
    __syncthreads();
    const int ct = tid & 63, rq = tid >> 6;
    const int c0 = ct * 2, r0 = rq * 16;
    float acc[16][2];
    #pragma unroll
    for (int r = 0; r < 16; r++) { acc[r][0] = 0.f; acc[r][1] = 0.f; }
    for (int k = 0; k < 256; k += 4) {
        float4 w0 = *(const float4*)&W_out[(c0 + 0) * 256 + k];
        float4 w1 = *(const float4*)&W_out[(c0 + 1) * 256 + k];
        #pragma unroll
        for (int r = 0; r < 16; r++) {
            float4 a = *(const float4*)&sm[(r0 + r) * 260 + k];
            acc[r][0] += a.x * w0.x + a.y * w0.y + a.z * w0.z + a.w * w0.w;
            acc[r][1] += a.x * w1.x + a.y * w1.y + a.z * w1.z + a.w * w1.w;
        }
    }
    __syncthreads();
    #pragma unroll
    for (int r = 0; r < 16; r++) {
        sm[(c0 + 0) * 66 + r0 + r] = acc[r][0];
        sm[(c0 + 1) * 66 + r0 + r] = acc[r][1];
    }
    __syncthreads();
    float* outb = out + (size_t)bb * CC * LL;
    for (int i = tid; i < 128 * 64; i += 256) {
        int cc2 = i >> 6, li = i & 63;
        outb[(size_t)cc2 * LL + l0 + li] = sm[cc2 * 66 + li];
    }
}

extern "C" void kernel_launch(void* const* d_in, const int* in_sizes, int n_in,
                              void* d_out, int out_size, void* d_ws, size_t ws_size,
                              hipStream_t stream)
{
    const float* x      = (const float*)d_in[0];
    const float* ln_w   = (const float*)d_in[1];
    const float* ln_b   = (const float*)d_in[2];
    const float* W_in   = (const float*)d_in[3];
    const float* conv_w = (const float*)d_in[4];
    const float* conv_b = (const float*)d_in[5];
    const float* W_x    = (const float*)d_in[6];
    const float* W_dt   = (const float*)d_in[7];
    const float* b_dt   = (const float*)d_in[8];
    const float* A_log  = (const float*)d_in[9];
    const float* D_par  = (const float*)d_in[10];
    const float* W_out  = (const float*)d_in[11];
    float* out = (float*)d_out;
    float* ws  = (float*)d_ws;

    const size_t NRD = (size_t)BB * LL * 256;     // 7,077,888 floats
    const size_t NBC = (size_t)BB * LL * 16;      //   442,368 floats
    float* xi    = ws;
    float* z     = ws + NRD;
    float* u     = ws + 2 * NRD;
    float* delta = ws + 3 * NRD;
    float* Bsb   = ws + 4 * NRD;
    float* Csb   = Bsb + NBC;
    float* prodA = Csb + NBC;
    float* accB  = prodA + (size_t)NCH * 8192;    // becomes hstart after k_scanB
    float* y     = xi;                            // xi dead after conv

    k_ln_gemm<<<864, 256, 0, stream>>>(x, ln_w, ln_b, W_in, xi, z);
    k_conv<<<BB * (LL / 4), 256, 0, stream>>>(xi, conv_w, conv_b, u);
    k_xdbl<<<216, 256, 0, stream>>>(u, W_x, W_dt, b_dt, Bsb, Csb, delta);
    k_scanA<<<2 * NCH, 256, 0, stream>>>(delta, u, Bsb, A_log, prodA, accB);
    k_scanB<<<512, 256, 0, stream>>>(prodA, accB);
    k_scanC<<<2 * NCH, 256, 0, stream>>>(delta, u, Bsb, Csb, z, A_log, D_par, accB, y);
    k_out<<<432, 256, 0, stream>>>(y, W_out, out);
}

// Round 4
// 256.132 us; speedup vs baseline: 1.8288x; 1.2861x over previous
//
#include <hip/hip_runtime.h>
#include <math.h>

#define BB 2
#define CC 128
#define LL 13824        // 24*24*24
#define DI 256          // d_inner
#define NST 16          // d_state
#define NCH 512         // scan chunks
#define TCH 27          // LL / NCH

typedef unsigned short ushort_t;
using s16x8 = __attribute__((ext_vector_type(8))) short;
using f32x4 = __attribute__((ext_vector_type(4))) float;

__device__ __forceinline__ float silu_f(float x) { return x / (1.f + __expf(-x)); }

__device__ __forceinline__ ushort_t bf16_rne(float f) {
    unsigned int u = __float_as_uint(f);
    unsigned int r = u + 0x7fffu + ((u >> 16) & 1u);
    return (ushort_t)(r >> 16);
}
__device__ __forceinline__ float bf16_to_f(ushort_t h) {
    return __uint_as_float((unsigned int)h << 16);
}

// ---------------- K0: split W_in, W_out into bf16 hi/lo ----------------
__global__ __launch_bounds__(256) void k_wsplit(
    const float* __restrict__ Win, const float* __restrict__ Wout,
    ushort_t* __restrict__ WinH, ushort_t* __restrict__ WinL,
    ushort_t* __restrict__ WoH, ushort_t* __restrict__ WoL)
{
    int i = blockIdx.x * 256 + threadIdx.x;
    if (i < 512 * 128) {
        float f = Win[i];
        ushort_t h = bf16_rne(f);
        WinH[i] = h; WinL[i] = bf16_rne(f - bf16_to_f(h));
    } else {
        int j = i - 512 * 128;
        if (j < 128 * 256) {
            float f = Wout[j];
            ushort_t h = bf16_rne(f);
            WoH[j] = h; WoL[j] = bf16_rne(f - bf16_to_f(h));
        }
    }
}

// ---------------- K1: LayerNorm + bf16x3 MFMA GEMM (xn @ W_in^T) -> xi, z ----------------
// 64 rows/block, 512 threads (8 waves); wave w covers 64 output cols.
__global__ __launch_bounds__(512) void k_ln_mfma(
    const float* __restrict__ x, const float* __restrict__ ln_w, const float* __restrict__ ln_b,
    const ushort_t* __restrict__ WinH, const ushort_t* __restrict__ WinL,
    float* __restrict__ xi, float* __restrict__ z)
{
    __shared__ float xl[64 * 133];
    __shared__ ushort_t ah[64 * 128];
    __shared__ ushort_t al[64 * 128];
    const int tid = threadIdx.x;
    const int bb = blockIdx.x / 216;
    const int l0 = (blockIdx.x % 216) * 64;
    const float* xb = x + (size_t)bb * CC * LL;

    // load x transposed: [li][c]
    for (int i = tid; i < 64 * 128; i += 512) {
        int c = i >> 6, li = i & 63;
        xl[li * 133 + c] = xb[(size_t)c * LL + l0 + li];
    }
    __syncthreads();
    // LN (8 threads/row) + convert to swizzled bf16 hi/lo
    {
        int row = tid >> 3, g = tid & 7;
        float s = 0.f, sq = 0.f;
        for (int k = g; k < 128; k += 8) { float v = xl[row * 133 + k]; s += v; sq += v * v; }
        s += __shfl_xor(s, 1); sq += __shfl_xor(sq, 1);
        s += __shfl_xor(s, 2); sq += __shfl_xor(sq, 2);
        s += __shfl_xor(s, 4); sq += __shfl_xor(sq, 4);
        float mu = s * (1.f / 128.f);
        float var = sq * (1.f / 128.f) - mu * mu;
        float rs = rsqrtf(var + 1e-5f);
        for (int k = g; k < 128; k += 8) {
            float v = (xl[row * 133 + k] - mu) * rs * ln_w[k] + ln_b[k];
            ushort_t hb = bf16_rne(v);
            ushort_t lb = bf16_rne(v - bf16_to_f(hb));
            int pos = row * 128 + ((((k >> 3) ^ (row & 7))) << 3) + (k & 7);
            ah[pos] = hb; al[pos] = lb;
        }
    }
    __syncthreads();

    // MFMA: wave w -> cols w*64..w*64+63 (w<4: xi, w>=4: z)
    const int w  = tid >> 6;
    const int l  = tid & 63;
    const int lr = l & 15;
    const int lk = l >> 4;
    f32x4 acc[4][4];
    #pragma unroll
    for (int m = 0; m < 4; m++)
        #pragma unroll
        for (int nt = 0; nt < 4; nt++) acc[m][nt] = (f32x4)0.f;

    const int n_base = (w & 3) * 64 + ((w >> 2) * 256);   // global col in [0,512)
    #pragma unroll
    for (int ks = 0; ks < 4; ks++) {
        s16x8 afh[4], afl[4];
        #pragma unroll
        for (int m = 0; m < 4; m++) {
            int r = m * 16 + lr;
            int ci = ks * 4 + lk;
            int off = r * 128 + ((ci ^ (r & 7)) << 3);
            afh[m] = *(const s16x8*)&ah[off];
            afl[m] = *(const s16x8*)&al[off];
        }
        #pragma unroll
        for (int nt = 0; nt < 4; nt++) {
            size_t woff = (size_t)(n_base + nt * 16 + lr) * 128 + ks * 32 + lk * 8;
            s16x8 wh = *(const s16x8*)&WinH[woff];
            s16x8 wl = *(const s16x8*)&WinL[woff];
            #pragma unroll
            for (int m = 0; m < 4; m++) {
                acc[m][nt] = __builtin_amdgcn_mfma_f32_16x16x32_bf16(afh[m], wh, acc[m][nt], 0, 0, 0);
                acc[m][nt] = __builtin_amdgcn_mfma_f32_16x16x32_bf16(afh[m], wl, acc[m][nt], 0, 0, 0);
                acc[m][nt] = __builtin_amdgcn_mfma_f32_16x16x32_bf16(afl[m], wh, acc[m][nt], 0, 0, 0);
            }
        }
    }
    // store: C row=(lk*4+q) within tile, col=lr
    float* dst = (w < 4) ? xi : z;
    const int nb = (w & 3) * 64;
    #pragma unroll
    for (int m = 0; m < 4; m++) {
        #pragma unroll
        for (int nt = 0; nt < 4; nt++) {
            #pragma unroll
            for (int q = 0; q < 4; q++) {
                int row = l0 + m * 16 + lk * 4 + q;
                int col = nb + nt * 16 + lr;
                dst[((size_t)bb * LL + row) * 256 + col] = acc[m][nt][q];
            }
        }
    }
}

// ---------------- K2: causal depthwise conv(4) + bias + SiLU -> u (4 t per thread) -------
__global__ __launch_bounds__(256) void k_conv(
    const float* __restrict__ xi, const float* __restrict__ conv_w, const float* __restrict__ conv_b,
    float* __restrict__ u)
{
    int idx = blockIdx.x * 256 + threadIdx.x;
    int d = idx & 255;
    int q = idx >> 8;
    int b = q / (LL / 4);
    int t0 = (q % (LL / 4)) * 4;
    size_t base = ((size_t)b * LL + t0) * 256 + d;
    float w0 = conv_w[d * 4 + 0], w1 = conv_w[d * 4 + 1];
    float w2 = conv_w[d * 4 + 2], w3 = conv_w[d * 4 + 3];
    float cb = conv_b[d];
    float x0, x1, x2;
    if (t0 == 0) { x0 = 0.f; x1 = 0.f; x2 = 0.f; }
    else { x0 = xi[base - 3 * 256]; x1 = xi[base - 2 * 256]; x2 = xi[base - 256]; }
    float x3 = xi[base];
    float x4 = xi[base + 256];
    float x5 = xi[base + 2 * 256];
    float x6 = xi[base + 3 * 256];
    u[base]           = silu_f(cb + w0 * x0 + w1 * x1 + w2 * x2 + w3 * x3);
    u[base + 256]     = silu_f(cb + w0 * x1 + w1 * x2 + w2 * x3 + w3 * x4);
    u[base + 2 * 256] = silu_f(cb + w0 * x2 + w1 * x3 + w2 * x4 + w3 * x5);
    u[base + 3 * 256] = silu_f(cb + w0 * x3 + w1 * x4 + w2 * x5 + w3 * x6);
}

// ---------------- K3: x_dbl = u @ W_x^T ; Bs, Cs; delta = softplus(dt_r@W_dt^T+b_dt) ----
__global__ __launch_bounds__(256) void k_xdbl(
    const float* __restrict__ u, const float* __restrict__ W_x, const float* __restrict__ W_dt,
    const float* __restrict__ b_dt, float* __restrict__ Bs, float* __restrict__ Cs,
    float* __restrict__ delta)
{
    __shared__ float u_l[128 * 64];
    __shared__ float wx[40 * 68];
    __shared__ float xdbl[128 * 41];
    __shared__ float wdt[256 * 9];
    const int tid = threadIdx.x;
    const size_t row0 = (size_t)blockIdx.x * 128;

    for (int i = tid; i < 2048; i += 256) wdt[(i >> 3) * 9 + (i & 7)] = W_dt[i];

    const int rt = tid >> 3;
    const int ct = tid & 7;
    float acc[4][5];
    #pragma unroll
    for (int r = 0; r < 4; r++)
        #pragma unroll
        for (int j = 0; j < 5; j++) acc[r][j] = 0.f;

    for (int kt = 0; kt < 4; kt++) {
        __syncthreads();
        for (int i = tid; i < 2048; i += 256) {
            int r = i >> 4, kq = i & 15;
            float4 v = *(const float4*)&u[(row0 + r) * 256 + kt * 64 + kq * 4];
            *(float4*)&u_l[r * 64 + ((kq ^ ((r >> 2) & 7)) << 2)] = v;
        }
        for (int i = tid; i < 640; i += 256) {
            int j = i >> 4, kq = i & 15;
            *(float4*)&wx[j * 68 + kq * 4] = *(const float4*)&W_x[j * 256 + kt * 64 + kq * 4];
        }
        __syncthreads();
        #pragma unroll 4
        for (int kq = 0; kq < 16; kq++) {
            float4 a[4], w[5];
            #pragma unroll
            for (int rr = 0; rr < 4; rr++) {
                int r = rt * 4 + rr;
                a[rr] = *(const float4*)&u_l[r * 64 + ((kq ^ (rt & 7)) << 2)];
            }
            #pragma unroll
            for (int jj = 0; jj < 5; jj++)
                w[jj] = *(const float4*)&wx[(ct * 5 + jj) * 68 + kq * 4];
            #pragma unroll
            for (int rr = 0; rr < 4; rr++)
                #pragma unroll
                for (int jj = 0; jj < 5; jj++)
                    acc[rr][jj] += a[rr].x * w[jj].x + a[rr].y * w[jj].y
                                 + a[rr].z * w[jj].z + a[rr].w * w[jj].w;
        }
    }
    __syncthreads();
    #pragma unroll
    for (int rr = 0; rr < 4; rr++) {
        int r = rt * 4 + rr;
        size_t grow = row0 + r;
        #pragma unroll
        for (int jj = 0; jj < 5; jj++) {
            int j = ct * 5 + jj;
            float v = acc[rr][jj];
            xdbl[r * 41 + j] = v;
            if (j >= 8 && j < 24)      Bs[grow * 16 + (j - 8)]  = v;
            else if (j >= 24)          Cs[grow * 16 + (j - 24)] = v;
        }
    }
    __syncthreads();
    for (int i = tid; i < 128 * 256; i += 256) {
        int r = i >> 8, dd = i & 255;
        float v = b_dt[dd];
        #pragma unroll
        for (int jj = 0; jj < 8; jj++) v += xdbl[r * 41 + jj] * wdt[dd * 9 + jj];
        float sp = (v > 20.f) ? v : log1pf(expf(v));
        delta[(row0 + r) * 256 + dd] = sp;
    }
}

// ---------------- K4a: per-chunk scan summaries; thread=(b,chunk,d), 16 states in regs ----
__global__ __launch_bounds__(256) void k_scanA(
    const float* __restrict__ delta, const float* __restrict__ u, const float* __restrict__ Bs,
    const float* __restrict__ A_log, float* __restrict__ prodA, float* __restrict__ accB)
{
    __shared__ float bs_l[TCH * 16];
    const int bb = blockIdx.x & 1;
    const int c  = blockIdx.x >> 1;
    const int dd = threadIdx.x;
    const size_t rbase = (size_t)bb * LL + (size_t)c * TCH;

    {
        const float4* src = (const float4*)(Bs + rbase * 16);
        float4* dst = (float4*)bs_l;
        for (int i = threadIdx.x; i < TCH * 4; i += 256) dst[i] = src[i];
    }
    __syncthreads();

    float Ac[16], h[16], pr[16];
    #pragma unroll
    for (int s = 0; s < 16; s++) {
        Ac[s] = -expf(A_log[dd * 16 + s]);
        h[s] = 0.f; pr[s] = 1.f;
    }
    for (int tt = 0; tt < TCH; tt++) {
        size_t ro = rbase + tt;
        float dt = delta[ro * 256 + dd];
        float uu = u[ro * 256 + dd];
        float du = dt * uu;
        const float4* bv = (const float4*)&bs_l[tt * 16];
        float4 b0 = bv[0], b1 = bv[1], b2 = bv[2], b3 = bv[3];
        float bsv[16] = {b0.x,b0.y,b0.z,b0.w, b1.x,b1.y,b1.z,b1.w,
                         b2.x,b2.y,b2.z,b2.w, b3.x,b3.y,b3.z,b3.w};
        #pragma unroll
        for (int s = 0; s < 16; s++) {
            float a = __expf(dt * Ac[s]);
            h[s] = a * h[s] + du * bsv[s];
            pr[s] *= a;
        }
    }
    size_t base = (size_t)c * 8192 + bb * 4096 + dd * 16;
    #pragma unroll
    for (int q = 0; q < 4; q++) {
        *(float4*)&prodA[base + q * 4] = make_float4(pr[q*4+0], pr[q*4+1], pr[q*4+2], pr[q*4+3]);
        *(float4*)&accB [base + q * 4] = make_float4(h [q*4+0], h [q*4+1], h [q*4+2], h [q*4+3]);
    }
}

// ---------------- K4b: block-parallel chunk-prefix; accB overwritten with hstart ---------
__global__ __launch_bounds__(256) void k_scanB(
    const float* __restrict__ prodA, float* __restrict__ accB)
{
    __shared__ float sA[16 * 528];
    __shared__ float sB[16 * 528];
    __shared__ float segA[16][17];
    __shared__ float segB[16][17];
    __shared__ float segH[16][17];
    const int bb = blockIdx.x >> 8;
    const int dd = blockIdx.x & 255;
    const int t = threadIdx.x;
    const size_t gbase = (size_t)bb * 4096 + dd * 16;

    for (int i = t; i < 2048; i += 256) {
        int c = i >> 2, sq = i & 3;
        size_t ga = (size_t)c * 8192 + gbase + sq * 4;
        float4 a = *(const float4*)&prodA[ga];
        float4 b = *(const float4*)&accB[ga];
        int cc = c + (c >> 5);
        sA[(4*sq+0) * 528 + cc] = a.x; sA[(4*sq+1) * 528 + cc] = a.y;
        sA[(4*sq+2) * 528 + cc] = a.z; sA[(4*sq+3) * 528 + cc] = a.w;
        sB[(4*sq+0) * 528 + cc] = b.x; sB[(4*sq+1) * 528 + cc] = b.y;
        sB[(4*sq+2) * 528 + cc] = b.z; sB[(4*sq+3) * 528 + cc] = b.w;
    }
    __syncthreads();

    const int s   = t >> 4;
    const int seg = t & 15;
    const int base = s * 528;
    const int c0 = seg * 32;
    float A = 1.f, Bv = 0.f;
    for (int k = 0; k < 32; k++) {
        int cc = c0 + seg + k;
        float a = sA[base + cc];
        float b = sB[base + cc];
        A *= a;
        Bv = a * Bv + b;
    }
    segA[s][seg] = A; segB[s][seg] = Bv;
    __syncthreads();
    if (seg == 0) {
        float h = 0.f;
        #pragma unroll
        for (int g = 0; g < 16; g++) {
            segH[s][g] = h;
            h = segA[s][g] * h + segB[s][g];
        }
    }
    __syncthreads();
    float h = segH[s][seg];
    for (int k = 0; k < 32; k++) {
        int c = c0 + k;
        int cc = c + seg;
        float a = sA[base + cc];
        float b = sB[base + cc];
        accB[(size_t)c * 8192 + gbase + s] = h;
        h = a * h + b;
    }
}

// ---------------- K4c: final scan with correct h0; fuse y=(Σh·C + u·D)·silu(z) ----------
__global__ __launch_bounds__(256) void k_scanC(
    const float* __restrict__ delta, const float* __restrict__ u, const float* __restrict__ Bs,
    const float* __restrict__ Cs, const float* __restrict__ z, const float* __restrict__ A_log,
    const float* __restrict__ D_param, const float* __restrict__ hstart, float* __restrict__ y)
{
    __shared__ float bs_l[TCH * 16];
    __shared__ float cs_l[TCH * 16];
    const int bb = blockIdx.x & 1;
    const int c  = blockIdx.x >> 1;
    const int dd = threadIdx.x;
    const size_t rbase = (size_t)bb * LL + (size_t)c * TCH;

    {
        const float4* srcB = (const float4*)(Bs + rbase * 16);
        const float4* srcC = (const float4*)(Cs + rbase * 16);
        float4* dstB = (float4*)bs_l;
        float4* dstC = (float4*)cs_l;
        for (int i = threadIdx.x; i < TCH * 4; i += 256) { dstB[i] = srcB[i]; dstC[i] = srcC[i]; }
    }
    __syncthreads();

    float Ac[16], h[16];
    #pragma unroll
    for (int s = 0; s < 16; s++) Ac[s] = -expf(A_log[dd * 16 + s]);
    size_t hbase = (size_t)c * 8192 + bb * 4096 + dd * 16;
    #pragma unroll
    for (int q = 0; q < 4; q++) {
        float4 hv = *(const float4*)&hstart[hbase + q * 4];
        h[q*4+0] = hv.x; h[q*4+1] = hv.y; h[q*4+2] = hv.z; h[q*4+3] = hv.w;
    }
    const float Dp = D_param[dd];

    for (int tt = 0; tt < TCH; tt++) {
        size_t ro = rbase + tt;
        float dt = delta[ro * 256 + dd];
        float uu = u[ro * 256 + dd];
        float du = dt * uu;
        const float4* bv = (const float4*)&bs_l[tt * 16];
        const float4* cv = (const float4*)&cs_l[tt * 16];
        float4 b0 = bv[0], b1 = bv[1], b2 = bv[2], b3 = bv[3];
        float4 c0 = cv[0], c1 = cv[1], c2 = cv[2], c3 = cv[3];
        float bsv[16] = {b0.x,b0.y,b0.z,b0.w, b1.x,b1.y,b1.z,b1.w,
                         b2.x,b2.y,b2.z,b2.w, b3.x,b3.y,b3.z,b3.w};
        float csv[16] = {c0.x,c0.y,c0.z,c0.w, c1.x,c1.y,c1.z,c1.w,
                         c2.x,c2.y,c2.z,c2.w, c3.x,c3.y,c3.z,c3.w};
        float p0 = 0.f, p1 = 0.f, p2 = 0.f, p3 = 0.f;
        #pragma unroll
        for (int q = 0; q < 4; q++) {
            float a0 = __expf(dt * Ac[q*4+0]);
            float a1 = __expf(dt * Ac[q*4+1]);
            float a2 = __expf(dt * Ac[q*4+2]);
            float a3 = __expf(dt * Ac[q*4+3]);
            h[q*4+0] = a0 * h[q*4+0] + du * bsv[q*4+0];
            h[q*4+1] = a1 * h[q*4+1] + du * bsv[q*4+1];
            h[q*4+2] = a2 * h[q*4+2] + du * bsv[q*4+2];
            h[q*4+3] = a3 * h[q*4+3] + du * bsv[q*4+3];
            p0 += h[q*4+0] * csv[q*4+0];
            p1 += h[q*4+1] * csv[q*4+1];
            p2 += h[q*4+2] * csv[q*4+2];
            p3 += h[q*4+3] * csv[q*4+3];
        }
        float p = (p0 + p1) + (p2 + p3);
        float zv = z[ro * 256 + dd];
        y[ro * 256 + dd] = (p + uu * Dp) * silu_f(zv);
    }
}

// ---------------- K5: out = y @ W_out^T via bf16x3 MFMA, transposed store ----------------
__global__ __launch_bounds__(256) void k_out_mfma(
    const float* __restrict__ y, const ushort_t* __restrict__ WoH, const ushort_t* __restrict__ WoL,
    float* __restrict__ out)
{
    __shared__ ushort_t abuf[2 * 64 * 256];   // ah | al ; reused as float tr[128*66]
    ushort_t* ah = abuf;
    ushort_t* al = abuf + 64 * 256;
    const int tid = threadIdx.x;
    const int bb = blockIdx.x / 216;
    const int l0 = (blockIdx.x % 216) * 64;
    const size_t row0 = (size_t)bb * LL + l0;

    for (int i = tid; i < 64 * 256; i += 256) {
        int r = i >> 8, k = i & 255;
        float v = y[(row0 + r) * 256 + k];
        ushort_t hb = bf16_rne(v);
        ushort_t lb = bf16_rne(v - bf16_to_f(hb));
        int pos = r * 256 + ((((k >> 3) ^ (r & 7))) << 3) + (k & 7);
        ah[pos] = hb; al[pos] = lb;
    }
    __syncthreads();

    const int w  = tid >> 6;    // 0..3 -> cols w*32..w*32+31
    const int l  = tid & 63;
    const int lr = l & 15;
    const int lk = l >> 4;
    f32x4 acc[4][2];
    #pragma unroll
    for (int m = 0; m < 4; m++) { acc[m][0] = (f32x4)0.f; acc[m][1] = (f32x4)0.f; }

    #pragma unroll
    for (int ks = 0; ks < 8; ks++) {
        s16x8 afh[4], afl[4];
        #pragma unroll
        for (int m = 0; m < 4; m++) {
            int r = m * 16 + lr;
            int ci = ks * 4 + lk;
            int off = r * 256 + ((ci ^ (r & 7)) << 3);
            afh[m] = *(const s16x8*)&ah[off];
            afl[m] = *(const s16x8*)&al[off];
        }
        #pragma unroll
        for (int nt = 0; nt < 2; nt++) {
            size_t woff = (size_t)(w * 32 + nt * 16 + lr) * 256 + ks * 32 + lk * 8;
            s16x8 wh = *(const s16x8*)&WoH[woff];
            s16x8 wl = *(const s16x8*)&WoL[woff];
            #pragma unroll
            for (int m = 0; m < 4; m++) {
                acc[m][nt] = __builtin_amdgcn_mfma_f32_16x16x32_bf16(afh[m], wh, acc[m][nt], 0, 0, 0);
                acc[m][nt] = __builtin_amdgcn_mfma_f32_16x16x32_bf16(afh[m], wl, acc[m][nt], 0, 0, 0);
                acc[m][nt] = __builtin_amdgcn_mfma_f32_16x16x32_bf16(afl[m], wh, acc[m][nt], 0, 0, 0);
            }
        }
    }
    __syncthreads();
    float* tr = (float*)abuf;   // 128*66 floats = 33792 B <= 64 KB
    #pragma unroll
    for (int m = 0; m < 4; m++)
        #pragma unroll
        for (int nt = 0; nt < 2; nt++)
            #pragma unroll
            for (int q = 0; q < 4; q++) {
                int r = m * 16 + lk * 4 + q;
                int c = w * 32 + nt * 16 + lr;
                tr[c * 66 + r] = acc[m][nt][q];
            }
    __syncthreads();
    for (int i = tid; i < 128 * 64; i += 256) {
        int c = i >> 6, li = i & 63;
        out[((size_t)bb * 128 + c) * LL + l0 + li] = tr[c * 66 + li];
    }
}

extern "C" void kernel_launch(void* const* d_in, const int* in_sizes, int n_in,
                              void* d_out, int out_size, void* d_ws, size_t ws_size,
                              hipStream_t stream)
{
    const float* x      = (const float*)d_in[0];
    const float* ln_w   = (const float*)d_in[1];
    const float* ln_b   = (const float*)d_in[2];
    const float* W_in   = (const float*)d_in[3];
    const float* conv_w = (const float*)d_in[4];
    const float* conv_b = (const float*)d_in[5];
    const float* W_x    = (const float*)d_in[6];
    const float* W_dt   = (const float*)d_in[7];
    const float* b_dt   = (const float*)d_in[8];
    const float* A_log  = (const float*)d_in[9];
    const float* D_par  = (const float*)d_in[10];
    const float* W_out  = (const float*)d_in[11];
    float* out = (float*)d_out;
    float* ws  = (float*)d_ws;

    const size_t NRD = (size_t)BB * LL * 256;     // 7,077,888 floats
    const size_t NBC = (size_t)BB * LL * 16;      //   442,368 floats
    float* xi    = ws;
    float* z     = ws + NRD;
    float* u     = ws + 2 * NRD;
    float* delta = ws + 3 * NRD;
    float* Bsb   = ws + 4 * NRD;
    float* Csb   = Bsb + NBC;
    float* prodA = Csb + NBC;
    float* accB  = prodA + (size_t)NCH * 8192;    // becomes hstart after k_scanB
    float* y     = xi;                            // xi dead after conv
    ushort_t* WinH = (ushort_t*)(accB + (size_t)NCH * 8192);
    ushort_t* WinL = WinH + 512 * 128;
    ushort_t* WoH  = WinL + 512 * 128;
    ushort_t* WoL  = WoH + 128 * 256;

    k_wsplit<<<384, 256, 0, stream>>>(W_in, W_out, WinH, WinL, WoH, WoL);
    k_ln_mfma<<<432, 512, 0, stream>>>(x, ln_w, ln_b, WinH, WinL, xi, z);
    k_conv<<<BB * (LL / 4), 256, 0, stream>>>(xi, conv_w, conv_b, u);
    k_xdbl<<<216, 256, 0, stream>>>(u, W_x, W_dt, b_dt, Bsb, Csb, delta);
    k_scanA<<<2 * NCH, 256, 0, stream>>>(delta, u, Bsb, A_log, prodA, accB);
    k_scanB<<<512, 256, 0, stream>>>(prodA, accB);
    k_scanC<<<2 * NCH, 256, 0, stream>>>(delta, u, Bsb, Csb, z, A_log, D_par, accB, y);
    k_out_mfma<<<432, 256, 0, stream>>>(y, WoH, WoL, out);
}

// Round 5
// 224.284 us; speedup vs baseline: 2.0885x; 1.1420x over previous
//
#include <hip/hip_runtime.h>
#include <math.h>

#define BB 2
#define CC 128
#define LL 13824        // 24*24*24
#define DI 256          // d_inner
#define NST 16          // d_state
#define NCH 512         // scan chunks
#define TCH 27          // LL / NCH

typedef unsigned short ushort_t;
using s16x8 = __attribute__((ext_vector_type(8))) short;
using f32x4 = __attribute__((ext_vector_type(4))) float;

__device__ __forceinline__ float silu_f(float x) { return x / (1.f + __expf(-x)); }

__device__ __forceinline__ ushort_t bf16_rne(float f) {
    unsigned int u = __float_as_uint(f);
    unsigned int r = u + 0x7fffu + ((u >> 16) & 1u);
    return (ushort_t)(r >> 16);
}
__device__ __forceinline__ float bf16_to_f(ushort_t h) {
    return __uint_as_float((unsigned int)h << 16);
}

// ---------------- K0: split W_in, W_out, W_x(padded to 48 rows) into bf16 hi/lo ----------
__global__ __launch_bounds__(256) void k_wsplit(
    const float* __restrict__ Win, const float* __restrict__ Wout, const float* __restrict__ Wx,
    ushort_t* __restrict__ WinH, ushort_t* __restrict__ WinL,
    ushort_t* __restrict__ WoH, ushort_t* __restrict__ WoL,
    ushort_t* __restrict__ WxH, ushort_t* __restrict__ WxL)
{
    int i = blockIdx.x * 256 + threadIdx.x;
    if (i < 512 * 128) {
        float f = Win[i];
        ushort_t h = bf16_rne(f);
        WinH[i] = h; WinL[i] = bf16_rne(f - bf16_to_f(h));
    } else if (i < 512 * 128 + 128 * 256) {
        int j = i - 512 * 128;
        float f = Wout[j];
        ushort_t h = bf16_rne(f);
        WoH[j] = h; WoL[j] = bf16_rne(f - bf16_to_f(h));
    } else {
        int m = i - (512 * 128 + 128 * 256);
        if (m < 48 * 256) {
            int j = m >> 8;
            float f = (j < 40) ? Wx[m] : 0.f;
            ushort_t h = bf16_rne(f);
            WxH[m] = h; WxL[m] = bf16_rne(f - bf16_to_f(h));
        }
    }
}

// ---------------- K1: LayerNorm + bf16x3 MFMA GEMM (xn @ W_in^T) -> xi, z ----------------
__global__ __launch_bounds__(512) void k_ln_mfma(
    const float* __restrict__ x, const float* __restrict__ ln_w, const float* __restrict__ ln_b,
    const ushort_t* __restrict__ WinH, const ushort_t* __restrict__ WinL,
    float* __restrict__ xi, float* __restrict__ z)
{
    __shared__ float xl[64 * 133];
    __shared__ ushort_t ah[64 * 128];
    __shared__ ushort_t al[64 * 128];
    const int tid = threadIdx.x;
    const int bb = blockIdx.x / 216;
    const int l0 = (blockIdx.x % 216) * 64;
    const float* xb = x + (size_t)bb * CC * LL;

    for (int i = tid; i < 64 * 128; i += 512) {
        int c = i >> 6, li = i & 63;
        xl[li * 133 + c] = xb[(size_t)c * LL + l0 + li];
    }
    __syncthreads();
    {
        int row = tid >> 3, g = tid & 7;
        float s = 0.f, sq = 0.f;
        for (int k = g; k < 128; k += 8) { float v = xl[row * 133 + k]; s += v; sq += v * v; }
        s += __shfl_xor(s, 1); sq += __shfl_xor(sq, 1);
        s += __shfl_xor(s, 2); sq += __shfl_xor(sq, 2);
        s += __shfl_xor(s, 4); sq += __shfl_xor(sq, 4);
        float mu = s * (1.f / 128.f);
        float var = sq * (1.f / 128.f) - mu * mu;
        float rs = rsqrtf(var + 1e-5f);
        for (int k = g; k < 128; k += 8) {
            float v = (xl[row * 133 + k] - mu) * rs * ln_w[k] + ln_b[k];
            ushort_t hb = bf16_rne(v);
            ushort_t lb = bf16_rne(v - bf16_to_f(hb));
            int pos = row * 128 + ((((k >> 3) ^ (row & 7))) << 3) + (k & 7);
            ah[pos] = hb; al[pos] = lb;
        }
    }
    __syncthreads();

    const int w  = tid >> 6;
    const int l  = tid & 63;
    const int lr = l & 15;
    const int lk = l >> 4;
    f32x4 acc[4][4];
    #pragma unroll
    for (int m = 0; m < 4; m++)
        #pragma unroll
        for (int nt = 0; nt < 4; nt++) acc[m][nt] = (f32x4)0.f;

    const int n_base = (w & 3) * 64 + ((w >> 2) * 256);
    #pragma unroll
    for (int ks = 0; ks < 4; ks++) {
        s16x8 afh[4], afl[4];
        #pragma unroll
        for (int m = 0; m < 4; m++) {
            int r = m * 16 + lr;
            int ci = ks * 4 + lk;
            int off = r * 128 + ((ci ^ (r & 7)) << 3);
            afh[m] = *(const s16x8*)&ah[off];
            afl[m] = *(const s16x8*)&al[off];
        }
        #pragma unroll
        for (int nt = 0; nt < 4; nt++) {
            size_t woff = (size_t)(n_base + nt * 16 + lr) * 128 + ks * 32 + lk * 8;
            s16x8 wh = *(const s16x8*)&WinH[woff];
            s16x8 wl = *(const s16x8*)&WinL[woff];
            #pragma unroll
            for (int m = 0; m < 4; m++) {
                acc[m][nt] = __builtin_amdgcn_mfma_f32_16x16x32_bf16(afh[m], wh, acc[m][nt], 0, 0, 0);
                acc[m][nt] = __builtin_amdgcn_mfma_f32_16x16x32_bf16(afh[m], wl, acc[m][nt], 0, 0, 0);
                acc[m][nt] = __builtin_amdgcn_mfma_f32_16x16x32_bf16(afl[m], wh, acc[m][nt], 0, 0, 0);
            }
        }
    }
    float* dst = (w < 4) ? xi : z;
    const int nb = (w & 3) * 64;
    #pragma unroll
    for (int m = 0; m < 4; m++) {
        #pragma unroll
        for (int nt = 0; nt < 4; nt++) {
            #pragma unroll
            for (int q = 0; q < 4; q++) {
                int row = l0 + m * 16 + lk * 4 + q;
                int col = nb + nt * 16 + lr;
                dst[((size_t)bb * LL + row) * 256 + col] = acc[m][nt][q];
            }
        }
    }
}

// ------- K2: fused conv(4)+SiLU -> u ; x_dbl via bf16x3 MFMA -> Bs,Cs ; delta ----------
__global__ __launch_bounds__(256) void k_conv_xdbl(
    const float* __restrict__ xi, const float* __restrict__ conv_w, const float* __restrict__ conv_b,
    const ushort_t* __restrict__ WxH, const ushort_t* __restrict__ WxL,
    const float* __restrict__ W_dt, const float* __restrict__ b_dt,
    float* __restrict__ u, float* __restrict__ Bs, float* __restrict__ Cs,
    float* __restrict__ delta)
{
    __shared__ ushort_t ah[64 * 256];
    __shared__ ushort_t al[64 * 256];
    __shared__ float dtr[64 * 9];
    __shared__ float wdt[256 * 9];
    const int tid = threadIdx.x;
    const int bb = blockIdx.x / 216;
    const int t0 = (blockIdx.x % 216) * 64;
    const size_t bbase = (size_t)bb * LL;

    for (int i = tid; i < 2048; i += 256) wdt[(i >> 3) * 9 + (i & 7)] = W_dt[i];

    // conv + silu: thread = column d; rolling window over 64 rows
    {
        const int d = tid;
        float w0 = conv_w[d * 4 + 0], w1 = conv_w[d * 4 + 1];
        float w2 = conv_w[d * 4 + 2], w3 = conv_w[d * 4 + 3];
        float cb = conv_b[d];
        float p0, p1, p2;
        if (t0 == 0) { p0 = 0.f; p1 = 0.f; p2 = 0.f; }
        else {
            p0 = xi[(bbase + t0 - 3) * 256 + d];
            p1 = xi[(bbase + t0 - 2) * 256 + d];
            p2 = xi[(bbase + t0 - 1) * 256 + d];
        }
        const int ci = d >> 3, dl = d & 7;
        #pragma unroll 4
        for (int r = 0; r < 64; r++) {
            float xv = xi[(bbase + t0 + r) * 256 + d];
            float uv = silu_f(cb + w0 * p0 + w1 * p1 + w2 * p2 + w3 * xv);
            u[(bbase + t0 + r) * 256 + d] = uv;
            ushort_t hb = bf16_rne(uv);
            ushort_t lb = bf16_rne(uv - bf16_to_f(hb));
            int pos = r * 256 + ((ci ^ (r & 7)) << 3) + dl;
            ah[pos] = hb; al[pos] = lb;
            p0 = p1; p1 = p2; p2 = xv;
        }
    }
    __syncthreads();

    // MFMA: x_dbl = u @ W_x^T  (N padded 40->48); wave w = m-tile (16 rows)
    const int w  = tid >> 6;
    const int l  = tid & 63;
    const int lr = l & 15;
    const int lk = l >> 4;
    f32x4 acc[3];
    acc[0] = (f32x4)0.f; acc[1] = (f32x4)0.f; acc[2] = (f32x4)0.f;
    #pragma unroll
    for (int ks = 0; ks < 8; ks++) {
        int r = w * 16 + lr;
        int ci = ks * 4 + lk;
        int off = r * 256 + ((ci ^ (r & 7)) << 3);
        s16x8 afh = *(const s16x8*)&ah[off];
        s16x8 afl = *(const s16x8*)&al[off];
        #pragma unroll
        for (int nt = 0; nt < 3; nt++) {
            size_t woff = (size_t)(nt * 16 + lr) * 256 + ks * 32 + lk * 8;
            s16x8 wh = *(const s16x8*)&WxH[woff];
            s16x8 wl = *(const s16x8*)&WxL[woff];
            acc[nt] = __builtin_amdgcn_mfma_f32_16x16x32_bf16(afh, wh, acc[nt], 0, 0, 0);
            acc[nt] = __builtin_amdgcn_mfma_f32_16x16x32_bf16(afh, wl, acc[nt], 0, 0, 0);
            acc[nt] = __builtin_amdgcn_mfma_f32_16x16x32_bf16(afl, wh, acc[nt], 0, 0, 0);
        }
    }
    #pragma unroll
    for (int nt = 0; nt < 3; nt++) {
        int j = nt * 16 + lr;
        #pragma unroll
        for (int q = 0; q < 4; q++) {
            int r = w * 16 + lk * 4 + q;
            size_t grow = bbase + t0 + r;
            float v = acc[nt][q];
            if (j < 8)       dtr[r * 9 + j] = v;
            else if (j < 24) Bs[grow * 16 + (j - 8)] = v;
            else if (j < 40) Cs[grow * 16 + (j - 24)] = v;
        }
    }
    __syncthreads();

    // delta = softplus(dt_r @ W_dt^T + b_dt): thread = column dd, 64 rows
    {
        const int dd = tid;
        float bd = b_dt[dd];
        float wv[8];
        #pragma unroll
        for (int j = 0; j < 8; j++) wv[j] = wdt[dd * 9 + j];
        for (int r = 0; r < 64; r++) {
            float v = bd;
            #pragma unroll
            for (int j = 0; j < 8; j++) v += dtr[r * 9 + j] * wv[j];
            float sp = fmaxf(v, 0.f) + log1pf(__expf(-fabsf(v)));
            delta[(bbase + t0 + r) * 256 + dd] = sp;
        }
    }
}

// ---------------- K4a: per-chunk scan summaries; thread=(b,chunk,d), 16 states in regs ----
__global__ __launch_bounds__(256) void k_scanA(
    const float* __restrict__ delta, const float* __restrict__ u, const float* __restrict__ Bs,
    const float* __restrict__ A_log, float* __restrict__ prodA, float* __restrict__ accB)
{
    __shared__ float bs_l[TCH * 16];
    const int bb = blockIdx.x & 1;
    const int c  = blockIdx.x >> 1;
    const int dd = threadIdx.x;
    const size_t rbase = (size_t)bb * LL + (size_t)c * TCH;

    {
        const float4* src = (const float4*)(Bs + rbase * 16);
        float4* dst = (float4*)bs_l;
        for (int i = threadIdx.x; i < TCH * 4; i += 256) dst[i] = src[i];
    }
    __syncthreads();

    float Ac[16], h[16], pr[16];
    #pragma unroll
    for (int s = 0; s < 16; s++) {
        Ac[s] = -expf(A_log[dd * 16 + s]);
        h[s] = 0.f; pr[s] = 1.f;
    }
    for (int tt = 0; tt < TCH; tt++) {
        size_t ro = rbase + tt;
        float dt = delta[ro * 256 + dd];
        float uu = u[ro * 256 + dd];
        float du = dt * uu;
        const float4* bv = (const float4*)&bs_l[tt * 16];
        float4 b0 = bv[0], b1 = bv[1], b2 = bv[2], b3 = bv[3];
        float bsv[16] = {b0.x,b0.y,b0.z,b0.w, b1.x,b1.y,b1.z,b1.w,
                         b2.x,b2.y,b2.z,b2.w, b3.x,b3.y,b3.z,b3.w};
        #pragma unroll
        for (int s = 0; s < 16; s++) {
            float a = __expf(dt * Ac[s]);
            h[s] = a * h[s] + du * bsv[s];
            pr[s] *= a;
        }
    }
    size_t base = (size_t)c * 8192 + bb * 4096 + dd * 16;
    #pragma unroll
    for (int q = 0; q < 4; q++) {
        *(float4*)&prodA[base + q * 4] = make_float4(pr[q*4+0], pr[q*4+1], pr[q*4+2], pr[q*4+3]);
        *(float4*)&accB [base + q * 4] = make_float4(h [q*4+0], h [q*4+1], h [q*4+2], h [q*4+3]);
    }
}

// ---------------- K4b: block-parallel chunk-prefix; accB overwritten with hstart ---------
__global__ __launch_bounds__(256) void k_scanB(
    const float* __restrict__ prodA, float* __restrict__ accB)
{
    __shared__ float sA[16 * 528];
    __shared__ float sB[16 * 528];
    __shared__ float segA[16][17];
    __shared__ float segB[16][17];
    __shared__ float segH[16][17];
    const int bb = blockIdx.x >> 8;
    const int dd = blockIdx.x & 255;
    const int t = threadIdx.x;
    const size_t gbase = (size_t)bb * 4096 + dd * 16;

    for (int i = t; i < 2048; i += 256) {
        int c = i >> 2, sq = i & 3;
        size_t ga = (size_t)c * 8192 + gbase + sq * 4;
        float4 a = *(const float4*)&prodA[ga];
        float4 b = *(const float4*)&accB[ga];
        int cc = c + (c >> 5);
        sA[(4*sq+0) * 528 + cc] = a.x; sA[(4*sq+1) * 528 + cc] = a.y;
        sA[(4*sq+2) * 528 + cc] = a.z; sA[(4*sq+3) * 528 + cc] = a.w;
        sB[(4*sq+0) * 528 + cc] = b.x; sB[(4*sq+1) * 528 + cc] = b.y;
        sB[(4*sq+2) * 528 + cc] = b.z; sB[(4*sq+3) * 528 + cc] = b.w;
    }
    __syncthreads();

    const int s   = t >> 4;
    const int seg = t & 15;
    const int base = s * 528;
    const int c0 = seg * 32;
    float A = 1.f, Bv = 0.f;
    for (int k = 0; k < 32; k++) {
        int cc = c0 + seg + k;
        float a = sA[base + cc];
        float b = sB[base + cc];
        A *= a;
        Bv = a * Bv + b;
    }
    segA[s][seg] = A; segB[s][seg] = Bv;
    __syncthreads();
    if (seg == 0) {
        float h = 0.f;
        #pragma unroll
        for (int g = 0; g < 16; g++) {
            segH[s][g] = h;
            h = segA[s][g] * h + segB[s][g];
        }
    }
    __syncthreads();
    float h = segH[s][seg];
    for (int k = 0; k < 32; k++) {
        int c = c0 + k;
        int cc = c + seg;
        float a = sA[base + cc];
        float b = sB[base + cc];
        accB[(size_t)c * 8192 + gbase + s] = h;
        h = a * h + b;
    }
}

// ---------------- K4c: final scan with correct h0; fuse y=(Σh·C + u·D)·silu(z) ----------
__global__ __launch_bounds__(256) void k_scanC(
    const float* __restrict__ delta, const float* __restrict__ u, const float* __restrict__ Bs,
    const float* __restrict__ Cs, const float* __restrict__ z, const float* __restrict__ A_log,
    const float* __restrict__ D_param, const float* __restrict__ hstart, float* __restrict__ y)
{
    __shared__ float bs_l[TCH * 16];
    __shared__ float cs_l[TCH * 16];
    const int bb = blockIdx.x & 1;
    const int c  = blockIdx.x >> 1;
    const int dd = threadIdx.x;
    const size_t rbase = (size_t)bb * LL + (size_t)c * TCH;

    {
        const float4* srcB = (const float4*)(Bs + rbase * 16);
        const float4* srcC = (const float4*)(Cs + rbase * 16);
        float4* dstB = (float4*)bs_l;
        float4* dstC = (float4*)cs_l;
        for (int i = threadIdx.x; i < TCH * 4; i += 256) { dstB[i] = srcB[i]; dstC[i] = srcC[i]; }
    }
    __syncthreads();

    float Ac[16], h[16];
    #pragma unroll
    for (int s = 0; s < 16; s++) Ac[s] = -expf(A_log[dd * 16 + s]);
    size_t hbase = (size_t)c * 8192 + bb * 4096 + dd * 16;
    #pragma unroll
    for (int q = 0; q < 4; q++) {
        float4 hv = *(const float4*)&hstart[hbase + q * 4];
        h[q*4+0] = hv.x; h[q*4+1] = hv.y; h[q*4+2] = hv.z; h[q*4+3] = hv.w;
    }
    const float Dp = D_param[dd];

    for (int tt = 0; tt < TCH; tt++) {
        size_t ro = rbase + tt;
        float dt = delta[ro * 256 + dd];
        float uu = u[ro * 256 + dd];
        float du = dt * uu;
        const float4* bv = (const float4*)&bs_l[tt * 16];
        const float4* cv = (const float4*)&cs_l[tt * 16];
        float4 b0 = bv[0], b1 = bv[1], b2 = bv[2], b3 = bv[3];
        float4 c0 = cv[0], c1 = cv[1], c2 = cv[2], c3 = cv[3];
        float bsv[16] = {b0.x,b0.y,b0.z,b0.w, b1.x,b1.y,b1.z,b1.w,
                         b2.x,b2.y,b2.z,b2.w, b3.x,b3.y,b3.z,b3.w};
        float csv[16] = {c0.x,c0.y,c0.z,c0.w, c1.x,c1.y,c1.z,c1.w,
                         c2.x,c2.y,c2.z,c2.w, c3.x,c3.y,c3.z,c3.w};
        float p0 = 0.f, p1 = 0.f, p2 = 0.f, p3 = 0.f;
        #pragma unroll
        for (int q = 0; q < 4; q++) {
            float a0 = __expf(dt * Ac[q*4+0]);
            float a1 = __expf(dt * Ac[q*4+1]);
            float a2 = __expf(dt * Ac[q*4+2]);
            float a3 = __expf(dt * Ac[q*4+3]);
            h[q*4+0] = a0 * h[q*4+0] + du * bsv[q*4+0];
            h[q*4+1] = a1 * h[q*4+1] + du * bsv[q*4+1];
            h[q*4+2] = a2 * h[q*4+2] + du * bsv[q*4+2];
            h[q*4+3] = a3 * h[q*4+3] + du * bsv[q*4+3];
            p0 += h[q*4+0] * csv[q*4+0];
            p1 += h[q*4+1] * csv[q*4+1];
            p2 += h[q*4+2] * csv[q*4+2];
            p3 += h[q*4+3] * csv[q*4+3];
        }
        float p = (p0 + p1) + (p2 + p3);
        float zv = z[ro * 256 + dd];
        y[ro * 256 + dd] = (p + uu * Dp) * silu_f(zv);
    }
}

// ---------------- K5: out = y @ W_out^T via bf16x3 MFMA, transposed store ----------------
__global__ __launch_bounds__(256) void k_out_mfma(
    const float* __restrict__ y, const ushort_t* __restrict__ WoH, const ushort_t* __restrict__ WoL,
    float* __restrict__ out)
{
    __shared__ ushort_t abuf[2 * 64 * 256];
    ushort_t* ah = abuf;
    ushort_t* al = abuf + 64 * 256;
    const int tid = threadIdx.x;
    const int bb = blockIdx.x / 216;
    const int l0 = (blockIdx.x % 216) * 64;
    const size_t row0 = (size_t)bb * LL + l0;

    for (int i = tid; i < 64 * 256; i += 256) {
        int r = i >> 8, k = i & 255;
        float v = y[(row0 + r) * 256 + k];
        ushort_t hb = bf16_rne(v);
        ushort_t lb = bf16_rne(v - bf16_to_f(hb));
        int pos = r * 256 + ((((k >> 3) ^ (r & 7))) << 3) + (k & 7);
        ah[pos] = hb; al[pos] = lb;
    }
    __syncthreads();

    const int w  = tid >> 6;
    const int l  = tid & 63;
    const int lr = l & 15;
    const int lk = l >> 4;
    f32x4 acc[4][2];
    #pragma unroll
    for (int m = 0; m < 4; m++) { acc[m][0] = (f32x4)0.f; acc[m][1] = (f32x4)0.f; }

    #pragma unroll
    for (int ks = 0; ks < 8; ks++) {
        s16x8 afh[4], afl[4];
        #pragma unroll
        for (int m = 0; m < 4; m++) {
            int r = m * 16 + lr;
            int ci = ks * 4 + lk;
            int off = r * 256 + ((ci ^ (r & 7)) << 3);
            afh[m] = *(const s16x8*)&ah[off];
            afl[m] = *(const s16x8*)&al[off];
        }
        #pragma unroll
        for (int nt = 0; nt < 2; nt++) {
            size_t woff = (size_t)(w * 32 + nt * 16 + lr) * 256 + ks * 32 + lk * 8;
            s16x8 wh = *(const s16x8*)&WoH[woff];
            s16x8 wl = *(const s16x8*)&WoL[woff];
            #pragma unroll
            for (int m = 0; m < 4; m++) {
                acc[m][nt] = __builtin_amdgcn_mfma_f32_16x16x32_bf16(afh[m], wh, acc[m][nt], 0, 0, 0);
                acc[m][nt] = __builtin_amdgcn_mfma_f32_16x16x32_bf16(afh[m], wl, acc[m][nt], 0, 0, 0);
                acc[m][nt] = __builtin_amdgcn_mfma_f32_16x16x32_bf16(afl[m], wh, acc[m][nt], 0, 0, 0);
            }
        }
    }
    __syncthreads();
    float* tr = (float*)abuf;
    #pragma unroll
    for (int m = 0; m < 4; m++)
        #pragma unroll
        for (int nt = 0; nt < 2; nt++)
            #pragma unroll
            for (int q = 0; q < 4; q++) {
                int r = m * 16 + lk * 4 + q;
                int c = w * 32 + nt * 16 + lr;
                tr[c * 66 + r] = acc[m][nt][q];
            }
    __syncthreads();
    for (int i = tid; i < 128 * 64; i += 256) {
        int c = i >> 6, li = i & 63;
        out[((size_t)bb * 128 + c) * LL + l0 + li] = tr[c * 66 + li];
    }
}

extern "C" void kernel_launch(void* const* d_in, const int* in_sizes, int n_in,
                              void* d_out, int out_size, void* d_ws, size_t ws_size,
                              hipStream_t stream)
{
    const float* x      = (const float*)d_in[0];
    const float* ln_w   = (const float*)d_in[1];
    const float* ln_b   = (const float*)d_in[2];
    const float* W_in   = (const float*)d_in[3];
    const float* conv_w = (const float*)d_in[4];
    const float* conv_b = (const float*)d_in[5];
    const float* W_x    = (const float*)d_in[6];
    const float* W_dt   = (const float*)d_in[7];
    const float* b_dt   = (const float*)d_in[8];
    const float* A_log  = (const float*)d_in[9];
    const float* D_par  = (const float*)d_in[10];
    const float* W_out  = (const float*)d_in[11];
    float* out = (float*)d_out;
    float* ws  = (float*)d_ws;

    const size_t NRD = (size_t)BB * LL * 256;     // 7,077,888 floats
    const size_t NBC = (size_t)BB * LL * 16;      //   442,368 floats
    float* xi    = ws;
    float* z     = ws + NRD;
    float* u     = ws + 2 * NRD;
    float* delta = ws + 3 * NRD;
    float* Bsb   = ws + 4 * NRD;
    float* Csb   = Bsb + NBC;
    float* prodA = Csb + NBC;
    float* accB  = prodA + (size_t)NCH * 8192;    // becomes hstart after k_scanB
    float* y     = xi;                            // xi dead after conv
    ushort_t* WinH = (ushort_t*)(accB + (size_t)NCH * 8192);
    ushort_t* WinL = WinH + 512 * 128;
    ushort_t* WoH  = WinL + 512 * 128;
    ushort_t* WoL  = WoH + 128 * 256;
    ushort_t* WxH  = WoL + 128 * 256;
    ushort_t* WxL  = WxH + 48 * 256;

    k_wsplit<<<432, 256, 0, stream>>>(W_in, W_out, W_x, WinH, WinL, WoH, WoL, WxH, WxL);
    k_ln_mfma<<<432, 512, 0, stream>>>(x, ln_w, ln_b, WinH, WinL, xi, z);
    k_conv_xdbl<<<432, 256, 0, stream>>>(xi, conv_w, conv_b, WxH, WxL, W_dt, b_dt,
                                         u, Bsb, Csb, delta);
    k_scanA<<<2 * NCH, 256, 0, stream>>>(delta, u, Bsb, A_log, prodA, accB);
    k_scanB<<<512, 256, 0, stream>>>(prodA, accB);
    k_scanC<<<2 * NCH, 256, 0, stream>>>(delta, u, Bsb, Csb, z, A_log, D_par, accB, y);
    k_out_mfma<<<432, 256, 0, stream>>>(y, WoH, WoL, out);
}

// Round 6
// 212.230 us; speedup vs baseline: 2.2071x; 1.0568x over previous
//
#include <hip/hip_runtime.h>
#include <math.h>

#define BB 2
#define CC 128
#define LL 13824        // 24*24*24
#define DI 256          // d_inner
#define NST 16          // d_state
#define NCH 512         // scan chunks
#define TCH 27          // LL / NCH

typedef unsigned short ushort_t;
using s16x8 = __attribute__((ext_vector_type(8))) short;
using f32x4 = __attribute__((ext_vector_type(4))) float;

__device__ __forceinline__ float silu_f(float x) { return x / (1.f + __expf(-x)); }

__device__ __forceinline__ ushort_t bf16_rne(float f) {
    unsigned int u = __float_as_uint(f);
    unsigned int r = u + 0x7fffu + ((u >> 16) & 1u);
    return (ushort_t)(r >> 16);
}
__device__ __forceinline__ float bf16_to_f(ushort_t h) {
    return __uint_as_float((unsigned int)h << 16);
}

// ---------------- K0: split W_in, W_out, W_x(padded to 48 rows) into bf16 hi/lo ----------
__global__ __launch_bounds__(256) void k_wsplit(
    const float* __restrict__ Win, const float* __restrict__ Wout, const float* __restrict__ Wx,
    ushort_t* __restrict__ WinH, ushort_t* __restrict__ WinL,
    ushort_t* __restrict__ WoH, ushort_t* __restrict__ WoL,
    ushort_t* __restrict__ WxH, ushort_t* __restrict__ WxL)
{
    int i = blockIdx.x * 256 + threadIdx.x;
    if (i < 512 * 128) {
        float f = Win[i];
        ushort_t h = bf16_rne(f);
        WinH[i] = h; WinL[i] = bf16_rne(f - bf16_to_f(h));
    } else if (i < 512 * 128 + 128 * 256) {
        int j = i - 512 * 128;
        float f = Wout[j];
        ushort_t h = bf16_rne(f);
        WoH[j] = h; WoL[j] = bf16_rne(f - bf16_to_f(h));
    } else {
        int m = i - (512 * 128 + 128 * 256);
        if (m < 48 * 256) {
            int j = m >> 8;
            float f = (j < 40) ? Wx[m] : 0.f;
            ushort_t h = bf16_rne(f);
            WxH[m] = h; WxL[m] = bf16_rne(f - bf16_to_f(h));
        }
    }
}

// ---------------- K1: LayerNorm + bf16x3 MFMA GEMM (xn @ W_in^T) -> xi, z ----------------
__global__ __launch_bounds__(512) void k_ln_mfma(
    const float* __restrict__ x, const float* __restrict__ ln_w, const float* __restrict__ ln_b,
    const ushort_t* __restrict__ WinH, const ushort_t* __restrict__ WinL,
    float* __restrict__ xi, float* __restrict__ z)
{
    __shared__ float xl[64 * 133];
    __shared__ ushort_t ah[64 * 128];
    __shared__ ushort_t al[64 * 128];
    const int tid = threadIdx.x;
    const int bb = blockIdx.x / 216;
    const int l0 = (blockIdx.x % 216) * 64;
    const float* xb = x + (size_t)bb * CC * LL;

    for (int i = tid; i < 64 * 128; i += 512) {
        int c = i >> 6, li = i & 63;
        xl[li * 133 + c] = xb[(size_t)c * LL + l0 + li];
    }
    __syncthreads();
    {
        int row = tid >> 3, g = tid & 7;
        float s = 0.f, sq = 0.f;
        for (int k = g; k < 128; k += 8) { float v = xl[row * 133 + k]; s += v; sq += v * v; }
        s += __shfl_xor(s, 1); sq += __shfl_xor(sq, 1);
        s += __shfl_xor(s, 2); sq += __shfl_xor(sq, 2);
        s += __shfl_xor(s, 4); sq += __shfl_xor(sq, 4);
        float mu = s * (1.f / 128.f);
        float var = sq * (1.f / 128.f) - mu * mu;
        float rs = rsqrtf(var + 1e-5f);
        for (int k = g; k < 128; k += 8) {
            float v = (xl[row * 133 + k] - mu) * rs * ln_w[k] + ln_b[k];
            ushort_t hb = bf16_rne(v);
            ushort_t lb = bf16_rne(v - bf16_to_f(hb));
            int pos = row * 128 + ((((k >> 3) ^ (row & 7))) << 3) + (k & 7);
            ah[pos] = hb; al[pos] = lb;
        }
    }
    __syncthreads();

    const int w  = tid >> 6;
    const int l  = tid & 63;
    const int lr = l & 15;
    const int lk = l >> 4;
    f32x4 acc[4][4];
    #pragma unroll
    for (int m = 0; m < 4; m++)
        #pragma unroll
        for (int nt = 0; nt < 4; nt++) acc[m][nt] = (f32x4)0.f;

    const int n_base = (w & 3) * 64 + ((w >> 2) * 256);
    #pragma unroll
    for (int ks = 0; ks < 4; ks++) {
        s16x8 afh[4], afl[4];
        #pragma unroll
        for (int m = 0; m < 4; m++) {
            int r = m * 16 + lr;
            int ci = ks * 4 + lk;
            int off = r * 128 + ((ci ^ (r & 7)) << 3);
            afh[m] = *(const s16x8*)&ah[off];
            afl[m] = *(const s16x8*)&al[off];
        }
        #pragma unroll
        for (int nt = 0; nt < 4; nt++) {
            size_t woff = (size_t)(n_base + nt * 16 + lr) * 128 + ks * 32 + lk * 8;
            s16x8 wh = *(const s16x8*)&WinH[woff];
            s16x8 wl = *(const s16x8*)&WinL[woff];
            #pragma unroll
            for (int m = 0; m < 4; m++) {
                acc[m][nt] = __builtin_amdgcn_mfma_f32_16x16x32_bf16(afh[m], wh, acc[m][nt], 0, 0, 0);
                acc[m][nt] = __builtin_amdgcn_mfma_f32_16x16x32_bf16(afh[m], wl, acc[m][nt], 0, 0, 0);
                acc[m][nt] = __builtin_amdgcn_mfma_f32_16x16x32_bf16(afl[m], wh, acc[m][nt], 0, 0, 0);
            }
        }
    }
    float* dst = (w < 4) ? xi : z;
    const int nb = (w & 3) * 64;
    #pragma unroll
    for (int m = 0; m < 4; m++) {
        #pragma unroll
        for (int nt = 0; nt < 4; nt++) {
            #pragma unroll
            for (int q = 0; q < 4; q++) {
                int row = l0 + m * 16 + lk * 4 + q;
                int col = nb + nt * 16 + lr;
                dst[((size_t)bb * LL + row) * 256 + col] = acc[m][nt][q];
            }
        }
    }
}

// ------- K2: fused conv(4)+SiLU -> u ; x_dbl via bf16x3 MFMA -> Bs,Cs ; delta ----------
// 32 rows/block, 864 blocks, ~34KB LDS -> 4 blocks/CU. Conv = 8 independent 4-row units.
__global__ __launch_bounds__(256, 4) void k_conv_xdbl(
    const float* __restrict__ xi, const float* __restrict__ conv_w, const float* __restrict__ conv_b,
    const ushort_t* __restrict__ WxH, const ushort_t* __restrict__ WxL,
    const float* __restrict__ W_dt, const float* __restrict__ b_dt,
    float* __restrict__ u, float* __restrict__ Bs, float* __restrict__ Cs,
    float* __restrict__ delta)
{
    __shared__ ushort_t ah[32 * 256];
    __shared__ ushort_t al[32 * 256];
    __shared__ float dtr[32 * 9];
    const int tid = threadIdx.x;
    const int bb = blockIdx.x / 432;
    const int t0 = (blockIdx.x % 432) * 32;
    const size_t bbase = (size_t)bb * LL;

    // ---- conv + silu: thread = column d; 8 independent 4-row units ----
    {
        const int d = tid;
        const float w0 = conv_w[d * 4 + 0], w1 = conv_w[d * 4 + 1];
        const float w2 = conv_w[d * 4 + 2], w3 = conv_w[d * 4 + 3];
        const float cb = conv_b[d];
        const int ci = d >> 3, dl = d & 7;
        #pragma unroll
        for (int k = 0; k < 8; k++) {
            const int t = t0 + k * 4;
            const size_t base = (bbase + t) * (size_t)256 + d;
            float a0, a1, a2;
            if (t == 0) { a0 = 0.f; a1 = 0.f; a2 = 0.f; }
            else { a0 = xi[base - 768]; a1 = xi[base - 512]; a2 = xi[base - 256]; }
            const float b0 = xi[base];
            const float b1 = xi[base + 256];
            const float b2 = xi[base + 512];
            const float b3 = xi[base + 768];
            const float u0 = silu_f(cb + w0 * a0 + w1 * a1 + w2 * a2 + w3 * b0);
            const float u1 = silu_f(cb + w0 * a1 + w1 * a2 + w2 * b0 + w3 * b1);
            const float u2 = silu_f(cb + w0 * a2 + w1 * b0 + w2 * b1 + w3 * b2);
            const float u3 = silu_f(cb + w0 * b0 + w1 * b1 + w2 * b2 + w3 * b3);
            u[base]       = u0;
            u[base + 256] = u1;
            u[base + 512] = u2;
            u[base + 768] = u3;
            const float uv[4] = {u0, u1, u2, u3};
            #pragma unroll
            for (int e = 0; e < 4; e++) {
                const int r = k * 4 + e;
                ushort_t hb = bf16_rne(uv[e]);
                ushort_t lb = bf16_rne(uv[e] - bf16_to_f(hb));
                int pos = r * 256 + ((ci ^ (r & 7)) << 3) + dl;
                ah[pos] = hb; al[pos] = lb;
            }
        }
    }
    __syncthreads();

    // ---- MFMA: x_dbl = u @ W_x^T (N padded 40->48); wave w<3: nt=w, m=0..1 ----
    const int w  = tid >> 6;
    const int l  = tid & 63;
    const int lr = l & 15;
    const int lk = l >> 4;
    if (w < 3) {
        f32x4 acc[2];
        acc[0] = (f32x4)0.f; acc[1] = (f32x4)0.f;
        #pragma unroll
        for (int ks = 0; ks < 8; ks++) {
            const size_t woff = (size_t)(w * 16 + lr) * 256 + ks * 32 + lk * 8;
            const s16x8 wh = *(const s16x8*)&WxH[woff];
            const s16x8 wl = *(const s16x8*)&WxL[woff];
            #pragma unroll
            for (int m = 0; m < 2; m++) {
                const int r = m * 16 + lr;
                const int ci = ks * 4 + lk;
                const int off = r * 256 + ((ci ^ (r & 7)) << 3);
                const s16x8 afh = *(const s16x8*)&ah[off];
                const s16x8 afl = *(const s16x8*)&al[off];
                acc[m] = __builtin_amdgcn_mfma_f32_16x16x32_bf16(afh, wh, acc[m], 0, 0, 0);
                acc[m] = __builtin_amdgcn_mfma_f32_16x16x32_bf16(afh, wl, acc[m], 0, 0, 0);
                acc[m] = __builtin_amdgcn_mfma_f32_16x16x32_bf16(afl, wh, acc[m], 0, 0, 0);
            }
        }
        const int j = w * 16 + lr;
        #pragma unroll
        for (int m = 0; m < 2; m++) {
            #pragma unroll
            for (int q = 0; q < 4; q++) {
                const int r = m * 16 + lk * 4 + q;
                const size_t grow = bbase + t0 + r;
                const float v = acc[m][q];
                if (j < 8)       dtr[r * 9 + j] = v;
                else if (j < 24) Bs[grow * 16 + (j - 8)] = v;
                else if (j < 40) Cs[grow * 16 + (j - 24)] = v;
            }
        }
    }
    __syncthreads();

    // ---- delta = softplus(dt_r @ W_dt^T + b_dt): thread = column dd, 32 rows ----
    {
        const int dd = tid;
        const float4 wva = *(const float4*)&W_dt[dd * 8];
        const float4 wvb = *(const float4*)&W_dt[dd * 8 + 4];
        const float bd = b_dt[dd];
        #pragma unroll 4
        for (int r = 0; r < 32; r++) {
            const float* dr = &dtr[r * 9];
            float v = bd
                + dr[0] * wva.x + dr[1] * wva.y + dr[2] * wva.z + dr[3] * wva.w
                + dr[4] * wvb.x + dr[5] * wvb.y + dr[6] * wvb.z + dr[7] * wvb.w;
            float sp = fmaxf(v, 0.f) + log1pf(__expf(-fabsf(v)));
            delta[(bbase + t0 + r) * 256 + dd] = sp;
        }
    }
}

// ---------------- K4a: per-chunk scan summaries; thread=(b,chunk,d), 16 states in regs ----
__global__ __launch_bounds__(256) void k_scanA(
    const float* __restrict__ delta, const float* __restrict__ u, const float* __restrict__ Bs,
    const float* __restrict__ A_log, float* __restrict__ prodA, float* __restrict__ accB)
{
    __shared__ float bs_l[TCH * 16];
    const int bb = blockIdx.x & 1;
    const int c  = blockIdx.x >> 1;
    const int dd = threadIdx.x;
    const size_t rbase = (size_t)bb * LL + (size_t)c * TCH;

    {
        const float4* src = (const float4*)(Bs + rbase * 16);
        float4* dst = (float4*)bs_l;
        for (int i = threadIdx.x; i < TCH * 4; i += 256) dst[i] = src[i];
    }
    __syncthreads();

    float Ac[16], h[16], pr[16];
    #pragma unroll
    for (int s = 0; s < 16; s++) {
        Ac[s] = -expf(A_log[dd * 16 + s]);
        h[s] = 0.f; pr[s] = 1.f;
    }
    for (int tt = 0; tt < TCH; tt++) {
        size_t ro = rbase + tt;
        float dt = delta[ro * 256 + dd];
        float uu = u[ro * 256 + dd];
        float du = dt * uu;
        const float4* bv = (const float4*)&bs_l[tt * 16];
        float4 b0 = bv[0], b1 = bv[1], b2 = bv[2], b3 = bv[3];
        float bsv[16] = {b0.x,b0.y,b0.z,b0.w, b1.x,b1.y,b1.z,b1.w,
                         b2.x,b2.y,b2.z,b2.w, b3.x,b3.y,b3.z,b3.w};
        #pragma unroll
        for (int s = 0; s < 16; s++) {
            float a = __expf(dt * Ac[s]);
            h[s] = a * h[s] + du * bsv[s];
            pr[s] *= a;
        }
    }
    size_t base = (size_t)c * 8192 + bb * 4096 + dd * 16;
    #pragma unroll
    for (int q = 0; q < 4; q++) {
        *(float4*)&prodA[base + q * 4] = make_float4(pr[q*4+0], pr[q*4+1], pr[q*4+2], pr[q*4+3]);
        *(float4*)&accB [base + q * 4] = make_float4(h [q*4+0], h [q*4+1], h [q*4+2], h [q*4+3]);
    }
}

// ---------------- K4b: block-parallel chunk-prefix; accB overwritten with hstart ---------
__global__ __launch_bounds__(256) void k_scanB(
    const float* __restrict__ prodA, float* __restrict__ accB)
{
    __shared__ float sA[16 * 528];
    __shared__ float sB[16 * 528];
    __shared__ float segA[16][17];
    __shared__ float segB[16][17];
    __shared__ float segH[16][17];
    const int bb = blockIdx.x >> 8;
    const int dd = blockIdx.x & 255;
    const int t = threadIdx.x;
    const size_t gbase = (size_t)bb * 4096 + dd * 16;

    for (int i = t; i < 2048; i += 256) {
        int c = i >> 2, sq = i & 3;
        size_t ga = (size_t)c * 8192 + gbase + sq * 4;
        float4 a = *(const float4*)&prodA[ga];
        float4 b = *(const float4*)&accB[ga];
        int cc = c + (c >> 5);
        sA[(4*sq+0) * 528 + cc] = a.x; sA[(4*sq+1) * 528 + cc] = a.y;
        sA[(4*sq+2) * 528 + cc] = a.z; sA[(4*sq+3) * 528 + cc] = a.w;
        sB[(4*sq+0) * 528 + cc] = b.x; sB[(4*sq+1) * 528 + cc] = b.y;
        sB[(4*sq+2) * 528 + cc] = b.z; sB[(4*sq+3) * 528 + cc] = b.w;
    }
    __syncthreads();

    const int s   = t >> 4;
    const int seg = t & 15;
    const int base = s * 528;
    const int c0 = seg * 32;
    float A = 1.f, Bv = 0.f;
    for (int k = 0; k < 32; k++) {
        int cc = c0 + seg + k;
        float a = sA[base + cc];
        float b = sB[base + cc];
        A *= a;
        Bv = a * Bv + b;
    }
    segA[s][seg] = A; segB[s][seg] = Bv;
    __syncthreads();
    if (seg == 0) {
        float h = 0.f;
        #pragma unroll
        for (int g = 0; g < 16; g++) {
            segH[s][g] = h;
            h = segA[s][g] * h + segB[s][g];
        }
    }
    __syncthreads();
    float h = segH[s][seg];
    for (int k = 0; k < 32; k++) {
        int c = c0 + k;
        int cc = c + seg;
        float a = sA[base + cc];
        float b = sB[base + cc];
        accB[(size_t)c * 8192 + gbase + s] = h;
        h = a * h + b;
    }
}

// ---------------- K4c: final scan with correct h0; fuse y=(Σh·C + u·D)·silu(z) ----------
__global__ __launch_bounds__(256) void k_scanC(
    const float* __restrict__ delta, const float* __restrict__ u, const float* __restrict__ Bs,
    const float* __restrict__ Cs, const float* __restrict__ z, const float* __restrict__ A_log,
    const float* __restrict__ D_param, const float* __restrict__ hstart, float* __restrict__ y)
{
    __shared__ float bs_l[TCH * 16];
    __shared__ float cs_l[TCH * 16];
    const int bb = blockIdx.x & 1;
    const int c  = blockIdx.x >> 1;
    const int dd = threadIdx.x;
    const size_t rbase = (size_t)bb * LL + (size_t)c * TCH;

    {
        const float4* srcB = (const float4*)(Bs + rbase * 16);
        const float4* srcC = (const float4*)(Cs + rbase * 16);
        float4* dstB = (float4*)bs_l;
        float4* dstC = (float4*)cs_l;
        for (int i = threadIdx.x; i < TCH * 4; i += 256) { dstB[i] = srcB[i]; dstC[i] = srcC[i]; }
    }
    __syncthreads();

    float Ac[16], h[16];
    #pragma unroll
    for (int s = 0; s < 16; s++) Ac[s] = -expf(A_log[dd * 16 + s]);
    size_t hbase = (size_t)c * 8192 + bb * 4096 + dd * 16;
    #pragma unroll
    for (int q = 0; q < 4; q++) {
        float4 hv = *(const float4*)&hstart[hbase + q * 4];
        h[q*4+0] = hv.x; h[q*4+1] = hv.y; h[q*4+2] = hv.z; h[q*4+3] = hv.w;
    }
    const float Dp = D_param[dd];

    for (int tt = 0; tt < TCH; tt++) {
        size_t ro = rbase + tt;
        float dt = delta[ro * 256 + dd];
        float uu = u[ro * 256 + dd];
        float du = dt * uu;
        const float4* bv = (const float4*)&bs_l[tt * 16];
        const float4* cv = (const float4*)&cs_l[tt * 16];
        float4 b0 = bv[0], b1 = bv[1], b2 = bv[2], b3 = bv[3];
        float4 c0 = cv[0], c1 = cv[1], c2 = cv[2], c3 = cv[3];
        float bsv[16] = {b0.x,b0.y,b0.z,b0.w, b1.x,b1.y,b1.z,b1.w,
                         b2.x,b2.y,b2.z,b2.w, b3.x,b3.y,b3.z,b3.w};
        float csv[16] = {c0.x,c0.y,c0.z,c0.w, c1.x,c1.y,c1.z,c1.w,
                         c2.x,c2.y,c2.z,c2.w, c3.x,c3.y,c3.z,c3.w};
        float p0 = 0.f, p1 = 0.f, p2 = 0.f, p3 = 0.f;
        #pragma unroll
        for (int q = 0; q < 4; q++) {
            float a0 = __expf(dt * Ac[q*4+0]);
            float a1 = __expf(dt * Ac[q*4+1]);
            float a2 = __expf(dt * Ac[q*4+2]);
            float a3 = __expf(dt * Ac[q*4+3]);
            h[q*4+0] = a0 * h[q*4+0] + du * bsv[q*4+0];
            h[q*4+1] = a1 * h[q*4+1] + du * bsv[q*4+1];
            h[q*4+2] = a2 * h[q*4+2] + du * bsv[q*4+2];
            h[q*4+3] = a3 * h[q*4+3] + du * bsv[q*4+3];
            p0 += h[q*4+0] * csv[q*4+0];
            p1 += h[q*4+1] * csv[q*4+1];
            p2 += h[q*4+2] * csv[q*4+2];
            p3 += h[q*4+3] * csv[q*4+3];
        }
        float p = (p0 + p1) + (p2 + p3);
        float zv = z[ro * 256 + dd];
        y[ro * 256 + dd] = (p + uu * Dp) * silu_f(zv);
    }
}

// ---------------- K5: out = y @ W_out^T via bf16x3 MFMA, transposed store ----------------
__global__ __launch_bounds__(256) void k_out_mfma(
    const float* __restrict__ y, const ushort_t* __restrict__ WoH, const ushort_t* __restrict__ WoL,
    float* __restrict__ out)
{
    __shared__ ushort_t abuf[2 * 64 * 256];
    ushort_t* ah = abuf;
    ushort_t* al = abuf + 64 * 256;
    const int tid = threadIdx.x;
    const int bb = blockIdx.x / 216;
    const int l0 = (blockIdx.x % 216) * 64;
    const size_t row0 = (size_t)bb * LL + l0;

    for (int i = tid; i < 64 * 256; i += 256) {
        int r = i >> 8, k = i & 255;
        float v = y[(row0 + r) * 256 + k];
        ushort_t hb = bf16_rne(v);
        ushort_t lb = bf16_rne(v - bf16_to_f(hb));
        int pos = r * 256 + ((((k >> 3) ^ (r & 7))) << 3) + (k & 7);
        ah[pos] = hb; al[pos] = lb;
    }
    __syncthreads();

    const int w  = tid >> 6;
    const int l  = tid & 63;
    const int lr = l & 15;
    const int lk = l >> 4;
    f32x4 acc[4][2];
    #pragma unroll
    for (int m = 0; m < 4; m++) { acc[m][0] = (f32x4)0.f; acc[m][1] = (f32x4)0.f; }

    #pragma unroll
    for (int ks = 0; ks < 8; ks++) {
        s16x8 afh[4], afl[4];
        #pragma unroll
        for (int m = 0; m < 4; m++) {
            int r = m * 16 + lr;
            int ci = ks * 4 + lk;
            int off = r * 256 + ((ci ^ (r & 7)) << 3);
            afh[m] = *(const s16x8*)&ah[off];
            afl[m] = *(const s16x8*)&al[off];
        }
        #pragma unroll
        for (int nt = 0; nt < 2; nt++) {
            size_t woff = (size_t)(w * 32 + nt * 16 + lr) * 256 + ks * 32 + lk * 8;
            s16x8 wh = *(const s16x8*)&WoH[woff];
            s16x8 wl = *(const s16x8*)&WoL[woff];
            #pragma unroll
            for (int m = 0; m < 4; m++) {
                acc[m][nt] = __builtin_amdgcn_mfma_f32_16x16x32_bf16(afh[m], wh, acc[m][nt], 0, 0, 0);
                acc[m][nt] = __builtin_amdgcn_mfma_f32_16x16x32_bf16(afh[m], wl, acc[m][nt], 0, 0, 0);
                acc[m][nt] = __builtin_amdgcn_mfma_f32_16x16x32_bf16(afl[m], wh, acc[m][nt], 0, 0, 0);
            }
        }
    }
    __syncthreads();
    float* tr = (float*)abuf;
    #pragma unroll
    for (int m = 0; m < 4; m++)
        #pragma unroll
        for (int nt = 0; nt < 2; nt++)
            #pragma unroll
            for (int q = 0; q < 4; q++) {
                int r = m * 16 + lk * 4 + q;
                int c = w * 32 + nt * 16 + lr;
                tr[c * 66 + r] = acc[m][nt][q];
            }
    __syncthreads();
    for (int i = tid; i < 128 * 64; i += 256) {
        int c = i >> 6, li = i & 63;
        out[((size_t)bb * 128 + c) * LL + l0 + li] = tr[c * 66 + li];
    }
}

extern "C" void kernel_launch(void* const* d_in, const int* in_sizes, int n_in,
                              void* d_out, int out_size, void* d_ws, size_t ws_size,
                              hipStream_t stream)
{
    const float* x      = (const float*)d_in[0];
    const float* ln_w   = (const float*)d_in[1];
    const float* ln_b   = (const float*)d_in[2];
    const float* W_in   = (const float*)d_in[3];
    const float* conv_w = (const float*)d_in[4];
    const float* conv_b = (const float*)d_in[5];
    const float* W_x    = (const float*)d_in[6];
    const float* W_dt   = (const float*)d_in[7];
    const float* b_dt   = (const float*)d_in[8];
    const float* A_log  = (const float*)d_in[9];
    const float* D_par  = (const float*)d_in[10];
    const float* W_out  = (const float*)d_in[11];
    float* out = (float*)d_out;
    float* ws  = (float*)d_ws;

    const size_t NRD = (size_t)BB * LL * 256;     // 7,077,888 floats
    const size_t NBC = (size_t)BB * LL * 16;      //   442,368 floats
    float* xi    = ws;
    float* z     = ws + NRD;
    float* u     = ws + 2 * NRD;
    float* delta = ws + 3 * NRD;
    float* Bsb   = ws + 4 * NRD;
    float* Csb   = Bsb + NBC;
    float* prodA = Csb + NBC;
    float* accB  = prodA + (size_t)NCH * 8192;    // becomes hstart after k_scanB
    float* y     = xi;                            // xi dead after conv
    ushort_t* WinH = (ushort_t*)(accB + (size_t)NCH * 8192);
    ushort_t* WinL = WinH + 512 * 128;
    ushort_t* WoH  = WinL + 512 * 128;
    ushort_t* WoL  = WoH + 128 * 256;
    ushort_t* WxH  = WoL + 128 * 256;
    ushort_t* WxL  = WxH + 48 * 256;

    k_wsplit<<<432, 256, 0, stream>>>(W_in, W_out, W_x, WinH, WinL, WoH, WoL, WxH, WxL);
    k_ln_mfma<<<432, 512, 0, stream>>>(x, ln_w, ln_b, WinH, WinL, xi, z);
    k_conv_xdbl<<<864, 256, 0, stream>>>(xi, conv_w, conv_b, WxH, WxL, W_dt, b_dt,
                                         u, Bsb, Csb, delta);
    k_scanA<<<2 * NCH, 256, 0, stream>>>(delta, u, Bsb, A_log, prodA, accB);
    k_scanB<<<512, 256, 0, stream>>>(prodA, accB);
    k_scanC<<<2 * NCH, 256, 0, stream>>>(delta, u, Bsb, Csb, z, A_log, D_par, accB, y);
    k_out_mfma<<<432, 256, 0, stream>>>(y, WoH, WoL, out);
}

// Round 7
// 187.467 us; speedup vs baseline: 2.4986x; 1.1321x over previous
//
#include <hip/hip_runtime.h>
#include <math.h>

#define BB 2
#define CC 128
#define LL 13824        // 24*24*24
#define DI 256          // d_inner
#define NCH 432         // scan chunks (= LL/32)
#define TCH 32          // chunk length

typedef unsigned short ushort_t;
using s16x8 = __attribute__((ext_vector_type(8))) short;
using f32x4 = __attribute__((ext_vector_type(4))) float;

__device__ __forceinline__ float silu_f(float x) { return x / (1.f + __expf(-x)); }

__device__ __forceinline__ ushort_t bf16_rne(float f) {
    unsigned int u = __float_as_uint(f);
    unsigned int r = u + 0x7fffu + ((u >> 16) & 1u);
    return (ushort_t)(r >> 16);
}
__device__ __forceinline__ float bf16_to_f(ushort_t h) {
    return __uint_as_float((unsigned int)h << 16);
}

// ---------------- K0: split W_in, W_out, W_x(padded to 48 rows) into bf16 hi/lo ----------
__global__ __launch_bounds__(256) void k_wsplit(
    const float* __restrict__ Win, const float* __restrict__ Wout, const float* __restrict__ Wx,
    ushort_t* __restrict__ WinH, ushort_t* __restrict__ WinL,
    ushort_t* __restrict__ WoH, ushort_t* __restrict__ WoL,
    ushort_t* __restrict__ WxH, ushort_t* __restrict__ WxL)
{
    int i = blockIdx.x * 256 + threadIdx.x;
    if (i < 512 * 128) {
        float f = Win[i];
        ushort_t h = bf16_rne(f);
        WinH[i] = h; WinL[i] = bf16_rne(f - bf16_to_f(h));
    } else if (i < 512 * 128 + 128 * 256) {
        int j = i - 512 * 128;
        float f = Wout[j];
        ushort_t h = bf16_rne(f);
        WoH[j] = h; WoL[j] = bf16_rne(f - bf16_to_f(h));
    } else {
        int m = i - (512 * 128 + 128 * 256);
        if (m < 48 * 256) {
            int j = m >> 8;
            float f = (j < 40) ? Wx[m] : 0.f;
            ushort_t h = bf16_rne(f);
            WxH[m] = h; WxL[m] = bf16_rne(f - bf16_to_f(h));
        }
    }
}

// ---------------- K1: LayerNorm + bf16x3 MFMA GEMM (xn @ W_in^T) -> xi, z ----------------
__global__ __launch_bounds__(512) void k_ln_mfma(
    const float* __restrict__ x, const float* __restrict__ ln_w, const float* __restrict__ ln_b,
    const ushort_t* __restrict__ WinH, const ushort_t* __restrict__ WinL,
    float* __restrict__ xi, float* __restrict__ z)
{
    __shared__ float xl[64 * 133];
    __shared__ ushort_t ah[64 * 128];
    __shared__ ushort_t al[64 * 128];
    const int tid = threadIdx.x;
    const int bb = blockIdx.x / 216;
    const int l0 = (blockIdx.x % 216) * 64;
    const float* xb = x + (size_t)bb * CC * LL;

    for (int i = tid; i < 64 * 128; i += 512) {
        int c = i >> 6, li = i & 63;
        xl[li * 133 + c] = xb[(size_t)c * LL + l0 + li];
    }
    __syncthreads();
    {
        int row = tid >> 3, g = tid & 7;
        float s = 0.f, sq = 0.f;
        for (int k = g; k < 128; k += 8) { float v = xl[row * 133 + k]; s += v; sq += v * v; }
        s += __shfl_xor(s, 1); sq += __shfl_xor(sq, 1);
        s += __shfl_xor(s, 2); sq += __shfl_xor(sq, 2);
        s += __shfl_xor(s, 4); sq += __shfl_xor(sq, 4);
        float mu = s * (1.f / 128.f);
        float var = sq * (1.f / 128.f) - mu * mu;
        float rs = rsqrtf(var + 1e-5f);
        for (int k = g; k < 128; k += 8) {
            float v = (xl[row * 133 + k] - mu) * rs * ln_w[k] + ln_b[k];
            ushort_t hb = bf16_rne(v);
            ushort_t lb = bf16_rne(v - bf16_to_f(hb));
            int pos = row * 128 + ((((k >> 3) ^ (row & 7))) << 3) + (k & 7);
            ah[pos] = hb; al[pos] = lb;
        }
    }
    __syncthreads();

    const int w  = tid >> 6;
    const int l  = tid & 63;
    const int lr = l & 15;
    const int lk = l >> 4;
    f32x4 acc[4][4];
    #pragma unroll
    for (int m = 0; m < 4; m++)
        #pragma unroll
        for (int nt = 0; nt < 4; nt++) acc[m][nt] = (f32x4)0.f;

    const int n_base = (w & 3) * 64 + ((w >> 2) * 256);
    #pragma unroll
    for (int ks = 0; ks < 4; ks++) {
        s16x8 afh[4], afl[4];
        #pragma unroll
        for (int m = 0; m < 4; m++) {
            int r = m * 16 + lr;
            int ci = ks * 4 + lk;
            int off = r * 128 + ((ci ^ (r & 7)) << 3);
            afh[m] = *(const s16x8*)&ah[off];
            afl[m] = *(const s16x8*)&al[off];
        }
        #pragma unroll
        for (int nt = 0; nt < 4; nt++) {
            size_t woff = (size_t)(n_base + nt * 16 + lr) * 128 + ks * 32 + lk * 8;
            s16x8 wh = *(const s16x8*)&WinH[woff];
            s16x8 wl = *(const s16x8*)&WinL[woff];
            #pragma unroll
            for (int m = 0; m < 4; m++) {
                acc[m][nt] = __builtin_amdgcn_mfma_f32_16x16x32_bf16(afh[m], wh, acc[m][nt], 0, 0, 0);
                acc[m][nt] = __builtin_amdgcn_mfma_f32_16x16x32_bf16(afh[m], wl, acc[m][nt], 0, 0, 0);
                acc[m][nt] = __builtin_amdgcn_mfma_f32_16x16x32_bf16(afl[m], wh, acc[m][nt], 0, 0, 0);
            }
        }
    }
    float* dst = (w < 4) ? xi : z;
    const int nb = (w & 3) * 64;
    #pragma unroll
    for (int m = 0; m < 4; m++) {
        #pragma unroll
        for (int nt = 0; nt < 4; nt++) {
            #pragma unroll
            for (int q = 0; q < 4; q++) {
                int row = l0 + m * 16 + lk * 4 + q;
                int col = nb + nt * 16 + lr;
                dst[((size_t)bb * LL + row) * 256 + col] = acc[m][nt][q];
            }
        }
    }
}

// ---------------- K2: streaming causal conv(4)+SiLU -> u (float4, 8 rows/thread) --------
__global__ __launch_bounds__(256) void k_conv(
    const float* __restrict__ xi, const float* __restrict__ conv_w, const float* __restrict__ conv_b,
    float* __restrict__ u)
{
    const int bb = blockIdx.x / NCH;
    const int t0 = (blockIdx.x % NCH) * 32 + (threadIdx.x >> 6) * 8;
    const int d4 = (threadIdx.x & 63) * 4;
    const size_t base = ((size_t)bb * LL + t0) * 256 + d4;

    // weights: w[k][e] for the 4 channels
    float4 r0 = *(const float4*)&conv_w[(d4 + 0) * 4];
    float4 r1 = *(const float4*)&conv_w[(d4 + 1) * 4];
    float4 r2 = *(const float4*)&conv_w[(d4 + 2) * 4];
    float4 r3 = *(const float4*)&conv_w[(d4 + 3) * 4];
    float4 cb = *(const float4*)&conv_b[d4];

    float4 xrow[11];
    if (t0 == 0) {
        xrow[0] = make_float4(0.f, 0.f, 0.f, 0.f);
        xrow[1] = xrow[0]; xrow[2] = xrow[0];
    } else {
        xrow[0] = *(const float4*)&xi[base - 3 * 256];
        xrow[1] = *(const float4*)&xi[base - 2 * 256];
        xrow[2] = *(const float4*)&xi[base - 1 * 256];
    }
    #pragma unroll
    for (int j = 0; j < 8; j++) xrow[3 + j] = *(const float4*)&xi[base + (size_t)j * 256];

    #pragma unroll
    for (int j = 0; j < 8; j++) {
        float4 a = xrow[j], b = xrow[j + 1], c = xrow[j + 2], d = xrow[j + 3];
        float4 o;
        o.x = silu_f(cb.x + r0.x * a.x + r0.y * b.x + r0.z * c.x + r0.w * d.x);
        o.y = silu_f(cb.y + r1.x * a.y + r1.y * b.y + r1.z * c.y + r1.w * d.y);
        o.z = silu_f(cb.z + r2.x * a.z + r2.y * b.z + r2.z * c.z + r2.w * d.z);
        o.w = silu_f(cb.w + r3.x * a.w + r3.y * b.w + r3.z * c.w + r3.w * d.w);
        *(float4*)&u[base + (size_t)j * 256] = o;
    }
}

// ------- K3: x_dbl via bf16x3 MFMA -> Bs,Cs ; delta ; fused scanA summaries -----------
// block = (b, chunk of 32 rows). LDS ~36KB -> 4 blocks/CU.
__global__ __launch_bounds__(256) void k_xdbl_scanA(
    const float* __restrict__ u,
    const ushort_t* __restrict__ WxH, const ushort_t* __restrict__ WxL,
    const float* __restrict__ W_dt, const float* __restrict__ b_dt,
    const float* __restrict__ A_log,
    float* __restrict__ Bs, float* __restrict__ Cs, float* __restrict__ delta,
    float* __restrict__ prodA, float* __restrict__ accB)
{
    __shared__ ushort_t ah[32 * 256];
    __shared__ ushort_t al[32 * 256];
    __shared__ float dtr[32 * 9];
    __shared__ float bs_l[32 * 16];
    const int tid = threadIdx.x;
    const int bb = blockIdx.x / NCH;
    const int c  = blockIdx.x % NCH;
    const int t0 = c * 32;
    const size_t bbase = (size_t)bb * LL;

    // phase 0: load u tile (float4), bf16-split into swizzled LDS
    for (int i = tid; i < 32 * 64; i += 256) {
        int r = i >> 6, kq = i & 63;
        float4 v = *(const float4*)&u[(bbase + t0 + r) * 256 + kq * 4];
        int ci = kq >> 1;
        int pos = r * 256 + ((ci ^ (r & 7)) << 3) + (kq & 1) * 4;
        float vv[4] = {v.x, v.y, v.z, v.w};
        #pragma unroll
        for (int e = 0; e < 4; e++) {
            ushort_t hb = bf16_rne(vv[e]);
            ah[pos + e] = hb;
            al[pos + e] = bf16_rne(vv[e] - bf16_to_f(hb));
        }
    }
    __syncthreads();

    // phase 1: MFMA x_dbl = u @ W_x^T (N padded 40->48); waves 0..2, nt=w, m=0..1
    const int w  = tid >> 6;
    const int l  = tid & 63;
    const int lr = l & 15;
    const int lk = l >> 4;
    if (w < 3) {
        f32x4 acc[2];
        acc[0] = (f32x4)0.f; acc[1] = (f32x4)0.f;
        #pragma unroll
        for (int ks = 0; ks < 8; ks++) {
            const size_t woff = (size_t)(w * 16 + lr) * 256 + ks * 32 + lk * 8;
            const s16x8 wh = *(const s16x8*)&WxH[woff];
            const s16x8 wl = *(const s16x8*)&WxL[woff];
            #pragma unroll
            for (int m = 0; m < 2; m++) {
                const int r = m * 16 + lr;
                const int ci = ks * 4 + lk;
                const int off = r * 256 + ((ci ^ (r & 7)) << 3);
                const s16x8 afh = *(const s16x8*)&ah[off];
                const s16x8 afl = *(const s16x8*)&al[off];
                acc[m] = __builtin_amdgcn_mfma_f32_16x16x32_bf16(afh, wh, acc[m], 0, 0, 0);
                acc[m] = __builtin_amdgcn_mfma_f32_16x16x32_bf16(afh, wl, acc[m], 0, 0, 0);
                acc[m] = __builtin_amdgcn_mfma_f32_16x16x32_bf16(afl, wh, acc[m], 0, 0, 0);
            }
        }
        const int j = w * 16 + lr;
        #pragma unroll
        for (int m = 0; m < 2; m++) {
            #pragma unroll
            for (int q = 0; q < 4; q++) {
                const int r = m * 16 + lk * 4 + q;
                const size_t grow = bbase + t0 + r;
                const float v = acc[m][q];
                if (j < 8)       dtr[r * 9 + j] = v;
                else if (j < 24) { Bs[grow * 16 + (j - 8)] = v; bs_l[r * 16 + (j - 8)] = v; }
                else if (j < 40) Cs[grow * 16 + (j - 24)] = v;
            }
        }
    }
    __syncthreads();

    // phase 2: delta + scanA chunk summary; thread = column d
    {
        const int d = tid;
        const float4 wva = *(const float4*)&W_dt[d * 8];
        const float4 wvb = *(const float4*)&W_dt[d * 8 + 4];
        const float bd = b_dt[d];
        const int ci = d >> 3, dl = d & 7;
        float Ac[16], h[16], pr[16];
        #pragma unroll
        for (int s = 0; s < 16; s++) {
            Ac[s] = -__expf(A_log[d * 16 + s]);
            h[s] = 0.f; pr[s] = 1.f;
        }
        for (int r = 0; r < 32; r++) {
            const float* dr = &dtr[r * 9];
            float v = bd
                + dr[0] * wva.x + dr[1] * wva.y + dr[2] * wva.z + dr[3] * wva.w
                + dr[4] * wvb.x + dr[5] * wvb.y + dr[6] * wvb.z + dr[7] * wvb.w;
            float dt = fmaxf(v, 0.f) + log1pf(__expf(-fabsf(v)));
            delta[(bbase + t0 + r) * 256 + d] = dt;
            const int pos = r * 256 + ((ci ^ (r & 7)) << 3) + dl;
            float uu = bf16_to_f(ah[pos]) + bf16_to_f(al[pos]);
            float du = dt * uu;
            const float4* bv = (const float4*)&bs_l[r * 16];
            float4 b0 = bv[0], b1 = bv[1], b2 = bv[2], b3 = bv[3];
            float bsv[16] = {b0.x,b0.y,b0.z,b0.w, b1.x,b1.y,b1.z,b1.w,
                             b2.x,b2.y,b2.z,b2.w, b3.x,b3.y,b3.z,b3.w};
            #pragma unroll
            for (int s = 0; s < 16; s++) {
                float a = __expf(dt * Ac[s]);
                h[s] = a * h[s] + du * bsv[s];
                pr[s] *= a;
            }
        }
        size_t base = (size_t)c * 8192 + bb * 4096 + d * 16;
        #pragma unroll
        for (int q = 0; q < 4; q++) {
            *(float4*)&prodA[base + q * 4] = make_float4(pr[q*4+0], pr[q*4+1], pr[q*4+2], pr[q*4+3]);
            *(float4*)&accB [base + q * 4] = make_float4(h [q*4+0], h [q*4+1], h [q*4+2], h [q*4+3]);
        }
    }
}

// ---------------- K4: block-parallel chunk-prefix over 432 chunks; accB -> hstart --------
__global__ __launch_bounds__(256) void k_scanB(
    const float* __restrict__ prodA, float* __restrict__ accB)
{
    __shared__ float sA[16 * 433];
    __shared__ float sB[16 * 433];
    __shared__ float segA[16][17];
    __shared__ float segB[16][17];
    __shared__ float segH[16][17];
    const int bb = blockIdx.x >> 8;
    const int dd = blockIdx.x & 255;
    const int t = threadIdx.x;
    const size_t gbase = (size_t)bb * 4096 + dd * 16;

    for (int i = t; i < NCH * 4; i += 256) {
        int c = i >> 2, sq = i & 3;
        size_t ga = (size_t)c * 8192 + gbase + sq * 4;
        float4 a = *(const float4*)&prodA[ga];
        float4 b = *(const float4*)&accB[ga];
        sA[(4*sq+0) * 433 + c] = a.x; sA[(4*sq+1) * 433 + c] = a.y;
        sA[(4*sq+2) * 433 + c] = a.z; sA[(4*sq+3) * 433 + c] = a.w;
        sB[(4*sq+0) * 433 + c] = b.x; sB[(4*sq+1) * 433 + c] = b.y;
        sB[(4*sq+2) * 433 + c] = b.z; sB[(4*sq+3) * 433 + c] = b.w;
    }
    __syncthreads();

    const int s   = t >> 4;
    const int seg = t & 15;
    const int base = s * 433;
    const int c0 = seg * 27;          // 16 segs x 27 = 432
    float A = 1.f, Bv = 0.f;
    for (int k = 0; k < 27; k++) {
        float a = sA[base + c0 + k];
        float b = sB[base + c0 + k];
        A *= a;
        Bv = a * Bv + b;
    }
    segA[s][seg] = A; segB[s][seg] = Bv;
    __syncthreads();
    if (seg == 0) {
        float h = 0.f;
        #pragma unroll
        for (int g = 0; g < 16; g++) {
            segH[s][g] = h;
            h = segA[s][g] * h + segB[s][g];
        }
    }
    __syncthreads();
    float h = segH[s][seg];
    for (int k = 0; k < 27; k++) {
        int c = c0 + k;
        float a = sA[base + c];
        float b = sB[base + c];
        accB[(size_t)c * 8192 + gbase + s] = h;
        h = a * h + b;
    }
}

// ------- K5: final scan (correct h0) + y=(Σh·C+u·D)·silu(z) + MFMA out-proj + store -----
__global__ __launch_bounds__(256) void k_scan_out(
    const float* __restrict__ delta, const float* __restrict__ u, const float* __restrict__ Bs,
    const float* __restrict__ Cs, const float* __restrict__ z, const float* __restrict__ A_log,
    const float* __restrict__ D_param, const float* __restrict__ hstart,
    const ushort_t* __restrict__ WoH, const ushort_t* __restrict__ WoL,
    float* __restrict__ out)
{
    __shared__ ushort_t abuf[2 * 32 * 256];   // y bf16 hi|lo ; reused as float tr[128*33]
    __shared__ float bs_l[32 * 16];
    __shared__ float cs_l[32 * 16];
    ushort_t* ah = abuf;
    ushort_t* al = abuf + 32 * 256;
    const int tid = threadIdx.x;
    const int bb = blockIdx.x / NCH;
    const int c  = blockIdx.x % NCH;
    const int t0 = c * 32;
    const size_t bbase = (size_t)bb * LL;

    if (tid < 128) {
        ((float4*)bs_l)[tid] = ((const float4*)(Bs + (bbase + t0) * 16))[tid];
        ((float4*)cs_l)[tid] = ((const float4*)(Cs + (bbase + t0) * 16))[tid];
    }
    __syncthreads();

    // phase 1: scan; thread = column d
    {
        const int d = tid;
        const int ci = d >> 3, dl = d & 7;
        float Ac[16], h[16];
        #pragma unroll
        for (int s = 0; s < 16; s++) Ac[s] = -__expf(A_log[d * 16 + s]);
        size_t hbase = (size_t)c * 8192 + bb * 4096 + d * 16;
        #pragma unroll
        for (int q = 0; q < 4; q++) {
            float4 hv = *(const float4*)&hstart[hbase + q * 4];
            h[q*4+0] = hv.x; h[q*4+1] = hv.y; h[q*4+2] = hv.z; h[q*4+3] = hv.w;
        }
        const float Dp = D_param[d];
        for (int r = 0; r < 32; r++) {
            const size_t ro = (bbase + t0 + r) * 256 + d;
            float dt = delta[ro];
            float uu = u[ro];
            float zv = z[ro];
            float du = dt * uu;
            const float4* bv = (const float4*)&bs_l[r * 16];
            const float4* cv = (const float4*)&cs_l[r * 16];
            float4 b0 = bv[0], b1 = bv[1], b2 = bv[2], b3 = bv[3];
            float4 c0v = cv[0], c1v = cv[1], c2v = cv[2], c3v = cv[3];
            float bsv[16] = {b0.x,b0.y,b0.z,b0.w, b1.x,b1.y,b1.z,b1.w,
                             b2.x,b2.y,b2.z,b2.w, b3.x,b3.y,b3.z,b3.w};
            float csv[16] = {c0v.x,c0v.y,c0v.z,c0v.w, c1v.x,c1v.y,c1v.z,c1v.w,
                             c2v.x,c2v.y,c2v.z,c2v.w, c3v.x,c3v.y,c3v.z,c3v.w};
            float p0 = 0.f, p1 = 0.f, p2 = 0.f, p3 = 0.f;
            #pragma unroll
            for (int q = 0; q < 4; q++) {
                float a0 = __expf(dt * Ac[q*4+0]);
                float a1 = __expf(dt * Ac[q*4+1]);
                float a2 = __expf(dt * Ac[q*4+2]);
                float a3 = __expf(dt * Ac[q*4+3]);
                h[q*4+0] = a0 * h[q*4+0] + du * bsv[q*4+0];
                h[q*4+1] = a1 * h[q*4+1] + du * bsv[q*4+1];
                h[q*4+2] = a2 * h[q*4+2] + du * bsv[q*4+2];
                h[q*4+3] = a3 * h[q*4+3] + du * bsv[q*4+3];
                p0 += h[q*4+0] * csv[q*4+0];
                p1 += h[q*4+1] * csv[q*4+1];
                p2 += h[q*4+2] * csv[q*4+2];
                p3 += h[q*4+3] * csv[q*4+3];
            }
            float y = (((p0 + p1) + (p2 + p3)) + uu * Dp) * silu_f(zv);
            ushort_t hb = bf16_rne(y);
            const int pos = r * 256 + ((ci ^ (r & 7)) << 3) + dl;
            ah[pos] = hb;
            al[pos] = bf16_rne(y - bf16_to_f(hb));
        }
    }
    __syncthreads();

    // phase 2: MFMA y @ W_out^T (M=32, N=128, K=256); wave w -> cols w*32..+31
    const int w  = tid >> 6;
    const int l  = tid & 63;
    const int lr = l & 15;
    const int lk = l >> 4;
    f32x4 acc[2][2];
    acc[0][0] = (f32x4)0.f; acc[0][1] = (f32x4)0.f;
    acc[1][0] = (f32x4)0.f; acc[1][1] = (f32x4)0.f;
    #pragma unroll
    for (int ks = 0; ks < 8; ks++) {
        s16x8 afh[2], afl[2];
        #pragma unroll
        for (int m = 0; m < 2; m++) {
            int r = m * 16 + lr;
            int ci = ks * 4 + lk;
            int off = r * 256 + ((ci ^ (r & 7)) << 3);
            afh[m] = *(const s16x8*)&ah[off];
            afl[m] = *(const s16x8*)&al[off];
        }
        #pragma unroll
        for (int nt = 0; nt < 2; nt++) {
            size_t woff = (size_t)(w * 32 + nt * 16 + lr) * 256 + ks * 32 + lk * 8;
            s16x8 wh = *(const s16x8*)&WoH[woff];
            s16x8 wl = *(const s16x8*)&WoL[woff];
            #pragma unroll
            for (int m = 0; m < 2; m++) {
                acc[m][nt] = __builtin_amdgcn_mfma_f32_16x16x32_bf16(afh[m], wh, acc[m][nt], 0, 0, 0);
                acc[m][nt] = __builtin_amdgcn_mfma_f32_16x16x32_bf16(afh[m], wl, acc[m][nt], 0, 0, 0);
                acc[m][nt] = __builtin_amdgcn_mfma_f32_16x16x32_bf16(afl[m], wh, acc[m][nt], 0, 0, 0);
            }
        }
    }
    __syncthreads();
    float* tr = (float*)abuf;   // 128 x 33 floats = 16.9KB <= 32KB
    #pragma unroll
    for (int m = 0; m < 2; m++)
        #pragma unroll
        for (int nt = 0; nt < 2; nt++)
            #pragma unroll
            for (int q = 0; q < 4; q++) {
                int r = m * 16 + lk * 4 + q;
                int ccol = w * 32 + nt * 16 + lr;
                tr[ccol * 33 + r] = acc[m][nt][q];
            }
    __syncthreads();
    for (int i = tid; i < 128 * 32; i += 256) {
        int cc = i >> 5, li = i & 31;
        out[((size_t)bb * 128 + cc) * LL + t0 + li] = tr[cc * 33 + li];
    }
}

extern "C" void kernel_launch(void* const* d_in, const int* in_sizes, int n_in,
                              void* d_out, int out_size, void* d_ws, size_t ws_size,
                              hipStream_t stream)
{
    const float* x      = (const float*)d_in[0];
    const float* ln_w   = (const float*)d_in[1];
    const float* ln_b   = (const float*)d_in[2];
    const float* W_in   = (const float*)d_in[3];
    const float* conv_w = (const float*)d_in[4];
    const float* conv_b = (const float*)d_in[5];
    const float* W_x    = (const float*)d_in[6];
    const float* W_dt   = (const float*)d_in[7];
    const float* b_dt   = (const float*)d_in[8];
    const float* A_log  = (const float*)d_in[9];
    const float* D_par  = (const float*)d_in[10];
    const float* W_out  = (const float*)d_in[11];
    float* out = (float*)d_out;
    float* ws  = (float*)d_ws;

    const size_t NRD = (size_t)BB * LL * 256;     // 7,077,888 floats
    const size_t NBC = (size_t)BB * LL * 16;      //   442,368 floats
    float* xi    = ws;
    float* z     = ws + NRD;
    float* u     = ws + 2 * NRD;
    float* delta = ws + 3 * NRD;
    float* Bsb   = ws + 4 * NRD;
    float* Csb   = Bsb + NBC;
    float* prodA = Csb + NBC;
    float* accB  = prodA + (size_t)NCH * 8192;    // becomes hstart after k_scanB
    ushort_t* WinH = (ushort_t*)(accB + (size_t)NCH * 8192);
    ushort_t* WinL = WinH + 512 * 128;
    ushort_t* WoH  = WinL + 512 * 128;
    ushort_t* WoL  = WoH + 128 * 256;
    ushort_t* WxH  = WoL + 128 * 256;
    ushort_t* WxL  = WxH + 48 * 256;

    k_wsplit<<<432, 256, 0, stream>>>(W_in, W_out, W_x, WinH, WinL, WoH, WoL, WxH, WxL);
    k_ln_mfma<<<432, 512, 0, stream>>>(x, ln_w, ln_b, WinH, WinL, xi, z);
    k_conv<<<BB * NCH, 256, 0, stream>>>(xi, conv_w, conv_b, u);
    k_xdbl_scanA<<<BB * NCH, 256, 0, stream>>>(u, WxH, WxL, W_dt, b_dt, A_log,
                                               Bsb, Csb, delta, prodA, accB);
    k_scanB<<<512, 256, 0, stream>>>(prodA, accB);
    k_scan_out<<<BB * NCH, 256, 0, stream>>>(delta, u, Bsb, Csb, z, A_log, D_par, accB,
                                             WoH, WoL, out);
}